// Round 2
// baseline (3497.447 us; speedup 1.0000x reference)
//
#include <hip/hip_runtime.h>
#include <cstdint>
#include <cstddef>

#define BQ 4
#define NSEQ 8192
#define DIMC 512
#define NH 8
#define DH 64
#define NM 256
#define NITER 6
#define KW 33
#define BHN (BQ*NH)
#define NSLICE 8
#define JS (NSEQ/NSLICE)

typedef unsigned short bf16u;

__device__ inline float b2f(bf16u u) { return __uint_as_float(((unsigned int)u) << 16); }
__device__ inline bf16u f2b(float f) {
  unsigned int u = __float_as_uint(f);
  unsigned int r = (u + 0x7fffu + ((u >> 16) & 1u)) >> 16;  // RNE
  return (bf16u)r;
}
__device__ inline void unpack8(uint4 p, float* dst) {
  dst[0] = __uint_as_float(p.x << 16); dst[1] = __uint_as_float(p.x & 0xffff0000u);
  dst[2] = __uint_as_float(p.y << 16); dst[3] = __uint_as_float(p.y & 0xffff0000u);
  dst[4] = __uint_as_float(p.z << 16); dst[5] = __uint_as_float(p.z & 0xffff0000u);
  dst[6] = __uint_as_float(p.w << 16); dst[7] = __uint_as_float(p.w & 0xffff0000u);
}

__global__ __launch_bounds__(256) void k_fill(float* out, int n, float v) {
  int i = blockIdx.x * 256 + threadIdx.x;
  if (i < n) out[i] = v;
}

// ---------------- qkv GEMM: [B*N,512] @ [512,1536] -> q(scaled)/k/v bf16 in [b,h,n,d]
__global__ __launch_bounds__(256) void k_gemm_qkv(
    const float* __restrict__ X, const float* __restrict__ W,
    bf16u* __restrict__ q, bf16u* __restrict__ kbuf, bf16u* __restrict__ vbuf) {
  __shared__ float As[16][64];
  __shared__ float Bs[16][64];
  const int row0 = blockIdx.x * 64;
  const int col0 = blockIdx.y * 64;
  const int tid = threadIdx.x;
  const int tx = tid & 15, ty = tid >> 4;
  const int ar = tid >> 2, ak = (tid & 3) << 2;
  const int bk = (tid >> 6) << 2, bc = tid & 63;
  float acc[4][4] = {};
  for (int k0 = 0; k0 < DIMC; k0 += 16) {
    float4 av = *(const float4*)(X + (size_t)(row0 + ar) * DIMC + k0 + ak);
    As[ak+0][ar] = av.x; As[ak+1][ar] = av.y; As[ak+2][ar] = av.z; As[ak+3][ar] = av.w;
    #pragma unroll
    for (int u = 0; u < 4; ++u)
      Bs[bk+u][bc] = W[(size_t)(k0 + bk + u) * (3*DIMC) + col0 + bc];
    __syncthreads();
    #pragma unroll
    for (int kk = 0; kk < 16; ++kk) {
      const float4 a = *(const float4*)&As[kk][ty<<2];
      const float4 b = *(const float4*)&Bs[kk][tx<<2];
      const float avr[4] = {a.x,a.y,a.z,a.w};
      const float bvr[4] = {b.x,b.y,b.z,b.w};
      #pragma unroll
      for (int i=0;i<4;++i)
        #pragma unroll
        for (int j=0;j<4;++j) acc[i][j] = fmaf(avr[i], bvr[j], acc[i][j]);
    }
    __syncthreads();
  }
  const int which = col0 >> 9;            // 0=q 1=k 2=v (uniform per block)
  const int h_ = (col0 & 511) >> 6;       // uniform per block
  bf16u* dst = (which==0) ? q : (which==1) ? kbuf : vbuf;
  const float mul = (which==0) ? 0.125f : 1.0f;
  #pragma unroll
  for (int i = 0; i < 4; ++i) {
    int gr = row0 + (ty<<2) + i;
    int b_ = gr >> 13, n_ = gr & (NSEQ-1);
    size_t base = ((((size_t)b_*NH + h_) * NSEQ) + n_) * DH + (tx<<2);
    ushort4 o;
    o.x = f2b(acc[i][0]*mul); o.y = f2b(acc[i][1]*mul);
    o.z = f2b(acc[i][2]*mul); o.w = f2b(acc[i][3]*mul);
    *(ushort4*)(dst + base) = o;
  }
}

// ---------------- landmark means over blocks of 32 (fp32 accumulate from bf16)
__global__ __launch_bounds__(256) void k_landmarks(
    const bf16u* __restrict__ q, const bf16u* __restrict__ kbuf,
    float* __restrict__ ql, float* __restrict__ klm) {
  int gi = blockIdx.x*4 + (threadIdx.x>>6);   // (b,h,i) flat, 0..8191
  int d = threadIdx.x & 63;
  int bh = gi >> 8, i = gi & 255;
  size_t srcoff = ((size_t)bh*NSEQ + (size_t)i*32)*DH + d;
  float sq = 0, sk = 0;
  #pragma unroll
  for (int j = 0; j < 32; ++j) {
    sq += b2f(q[srcoff + (size_t)j*DH]);
    sk += b2f(kbuf[srcoff + (size_t)j*DH]);
  }
  ql[(size_t)gi*DH + d] = sq * (1.0f/32.0f);
  klm[(size_t)gi*DH + d] = sk * (1.0f/32.0f);
}

// ---------------- attn2 = softmax(ql @ klm^T), one WG per bh, thread=row (all fp32)
__global__ __launch_bounds__(256) void k_attn2(
    const float* __restrict__ ql, const float* __restrict__ klm, float* __restrict__ a2) {
  __shared__ float kls[NM*DH];  // 64KB
  int bh = blockIdx.x, tid = threadIdx.x;
  const float* klb = klm + (size_t)bh*NM*DH;
  for (int i = tid*4; i < NM*DH; i += 1024) *(float4*)&kls[i] = *(const float4*)&klb[i];
  __syncthreads();
  float qr[DH];
  const float* qb = ql + ((size_t)bh*NM + tid)*DH;
  #pragma unroll
  for (int d = 0; d < DH; ++d) qr[d] = qb[d];
  float* arow = a2 + ((size_t)bh*NM + tid)*NM;
  float ssum = 0;
  for (int j = 0; j < NM; ++j) {
    float d0=0,d1=0,d2=0,d3=0;
    #pragma unroll
    for (int d = 0; d < DH; d += 4) {
      d0 = fmaf(qr[d+0], kls[j*DH+d+0], d0);
      d1 = fmaf(qr[d+1], kls[j*DH+d+1], d1);
      d2 = fmaf(qr[d+2], kls[j*DH+d+2], d2);
      d3 = fmaf(qr[d+3], kls[j*DH+d+3], d3);
    }
    float p = __expf((d0+d1)+(d2+d3));
    ssum += p;
    arow[j] = p;
  }
  float inv = 1.0f/ssum;
  for (int j = 0; j < NM; ++j) arow[j] *= inv;
}

// ---------------- pinv init reductions (global maxes, nonneg -> uint atomicMax)
__global__ void k_zero_scal(unsigned* scal) { if (threadIdx.x < 2) scal[threadIdx.x] = 0u; }

__global__ __launch_bounds__(256) void k_pinv_reduce(const float* __restrict__ a2, unsigned* scal) {
  int bh = blockIdx.x, t = threadIdx.x;
  const float* A = a2 + (size_t)bh*NM*NM;
  float rs = 0, cs = 0;
  for (int j = 0; j < NM; ++j) rs += fabsf(A[(size_t)t*NM + j]);
  for (int i = 0; i < NM; ++i) cs += fabsf(A[(size_t)i*NM + t]);
  __shared__ float red[256];
  red[t] = rs; __syncthreads();
  for (int s = 128; s > 0; s >>= 1) { if (t < s) red[t] = fmaxf(red[t], red[t+s]); __syncthreads(); }
  if (t == 0) atomicMax(scal+0, __float_as_uint(red[0]));
  __syncthreads();
  red[t] = cs; __syncthreads();
  for (int s = 128; s > 0; s >>= 1) { if (t < s) red[t] = fmaxf(red[t], red[t+s]); __syncthreads(); }
  if (t == 0) atomicMax(scal+1, __float_as_uint(red[0]));
}

__global__ __launch_bounds__(256) void k_zinit(
    const float* __restrict__ a2, const unsigned* __restrict__ scal, float* __restrict__ z) {
  size_t idx = (size_t)blockIdx.x*256 + threadIdx.x;  // 32*256*256 total
  int bh = (int)(idx >> 16);
  int ij = (int)(idx & 65535);
  int i = ij >> 8, j = ij & 255;
  float denom = __uint_as_float(scal[0]) * __uint_as_float(scal[1]);
  z[idx] = a2[((size_t)bh<<16) + ((size_t)j<<8) + i] / denom;
}

// ---------------- batched 256x256x256 GEMM: C = alpha*(A@B') + betaI*I, B'=(BMODE? 7I-B : B)
template<int BMODE>
__global__ __launch_bounds__(256) void k_gemm256(
    const float* __restrict__ A, const float* __restrict__ Bm, float* __restrict__ C,
    float alpha, float betaI) {
  __shared__ float As[32][64];
  __shared__ float Bs[32][64];
  const int bh = blockIdx.y;
  const int tm = blockIdx.x & 3, tn = blockIdx.x >> 2;
  const size_t base = (size_t)bh << 16;
  const int row0 = tm*64, col0 = tn*64;
  const int tid = threadIdx.x;
  const int tx = tid & 15, ty = tid >> 4;
  const int ar = tid >> 2, ak = (tid & 3) << 3;
  const int br = tid >> 3, bc0 = (tid & 7) << 3;
  float acc[4][4] = {};
  for (int k0 = 0; k0 < 256; k0 += 32) {
    float4 a0 = *(const float4*)(A + base + (size_t)(row0+ar)*256 + k0 + ak);
    float4 a1 = *(const float4*)(A + base + (size_t)(row0+ar)*256 + k0 + ak + 4);
    As[ak+0][ar]=a0.x; As[ak+1][ar]=a0.y; As[ak+2][ar]=a0.z; As[ak+3][ar]=a0.w;
    As[ak+4][ar]=a1.x; As[ak+5][ar]=a1.y; As[ak+6][ar]=a1.z; As[ak+7][ar]=a1.w;
    float4 b0 = *(const float4*)(Bm + base + (size_t)(k0+br)*256 + col0 + bc0);
    float4 b1 = *(const float4*)(Bm + base + (size_t)(k0+br)*256 + col0 + bc0 + 4);
    if (BMODE == 1) {
      const int kg = k0 + br;
      float bv[8] = {b0.x,b0.y,b0.z,b0.w,b1.x,b1.y,b1.z,b1.w};
      #pragma unroll
      for (int u = 0; u < 8; ++u)
        Bs[br][bc0+u] = ((col0 + bc0 + u) == kg ? 7.0f : 0.0f) - bv[u];
    } else {
      *(float4*)&Bs[br][bc0] = b0;
      *(float4*)&Bs[br][bc0+4] = b1;
    }
    __syncthreads();
    #pragma unroll
    for (int kk = 0; kk < 32; ++kk) {
      const float4 a = *(const float4*)&As[kk][ty<<2];
      const float4 b = *(const float4*)&Bs[kk][tx<<2];
      const float avr[4] = {a.x,a.y,a.z,a.w};
      const float bvr[4] = {b.x,b.y,b.z,b.w};
      #pragma unroll
      for (int i=0;i<4;++i)
        #pragma unroll
        for (int j=0;j<4;++j) acc[i][j] = fmaf(avr[i], bvr[j], acc[i][j]);
    }
    __syncthreads();
  }
  #pragma unroll
  for (int i = 0; i < 4; ++i) {
    int gr = row0 + (ty<<2) + i;
    float o[4];
    #pragma unroll
    for (int j = 0; j < 4; ++j) {
      int gc = col0 + (tx<<2) + j;
      o[j] = alpha*acc[i][j] + ((gr==gc) ? betaI : 0.0f);
    }
    *(float4*)(C + base + (size_t)gr*256 + col0 + (tx<<2)) = make_float4(o[0],o[1],o[2],o[3]);
  }
}

// ---------------- fused attn3 softmax @ v, sliced over j; partials to fpart
__global__ __launch_bounds__(256) void k_attn3v(
    const float* __restrict__ ql, const bf16u* __restrict__ kmat, const bf16u* __restrict__ vmat,
    float* __restrict__ fpart) {
  __shared__ float Ks[64][68];
  __shared__ float Vs[64][68];
  const int sl = blockIdx.x;   // 0..NSLICE-1
  const int bh = blockIdx.y;   // 0..31
  const int tid = threadIdx.x; // landmark row
  float qr[DH];
  const float* qb = ql + ((size_t)bh*NM + tid)*DH;
  #pragma unroll
  for (int d = 0; d < DH; ++d) qr[d] = qb[d];
  float acc[DH] = {};
  float ssum = 0;
  const int lr = tid >> 2, lc = (tid & 3) << 4;
  for (int j0 = sl*JS; j0 < sl*JS + JS; j0 += 64) {
    const bf16u* kb = kmat + ((size_t)bh*NSEQ + j0 + lr)*DH + lc;
    const bf16u* vb = vmat + ((size_t)bh*NSEQ + j0 + lr)*DH + lc;
    uint4 kp0 = *(const uint4*)kb;       uint4 kp1 = *(const uint4*)(kb + 8);
    uint4 vp0 = *(const uint4*)vb;       uint4 vp1 = *(const uint4*)(vb + 8);
    unpack8(kp0, &Ks[lr][lc]); unpack8(kp1, &Ks[lr][lc+8]);
    unpack8(vp0, &Vs[lr][lc]); unpack8(vp1, &Vs[lr][lc+8]);
    __syncthreads();
    for (int jj = 0; jj < 64; ++jj) {
      float d0=0,d1=0,d2=0,d3=0;
      #pragma unroll
      for (int d = 0; d < DH; d += 4) {
        d0 = fmaf(qr[d+0], Ks[jj][d+0], d0);
        d1 = fmaf(qr[d+1], Ks[jj][d+1], d1);
        d2 = fmaf(qr[d+2], Ks[jj][d+2], d2);
        d3 = fmaf(qr[d+3], Ks[jj][d+3], d3);
      }
      float p = __expf((d0+d1)+(d2+d3));
      ssum += p;
      #pragma unroll
      for (int d = 0; d < DH; ++d) acc[d] = fmaf(p, Vs[jj][d], acc[d]);
    }
    __syncthreads();
  }
  float* fp = fpart + (((size_t)bh*NSLICE + sl)*NM + tid)*65;
  #pragma unroll
  for (int d = 0; d < DH; ++d) fp[d] = acc[d];
  fp[64] = ssum;
}

__global__ __launch_bounds__(256) void k_attn3v_combine(
    const float* __restrict__ fpart, float* __restrict__ w1) {
  int gi = blockIdx.x*4 + (threadIdx.x>>6);  // bh*256 + i
  int d = threadIdx.x & 63;
  int bh = gi >> 8, i = gi & 255;
  float accd = 0, ssum = 0;
  #pragma unroll
  for (int s = 0; s < NSLICE; ++s) {
    const float* fp = fpart + (((size_t)bh*NSLICE + s)*NM + i)*65;
    accd += fp[d];
    ssum += fp[64];
  }
  w1[(size_t)gi*DH + d] = accd / ssum;
}

// ---------------- w2 = pinv(z) @ w1, one WG per bh, thread=row (fp32)
__global__ __launch_bounds__(256) void k_w2(
    const float* __restrict__ z, const float* __restrict__ w1, float* __restrict__ w2) {
  __shared__ float W1s[NM*DH];  // 64KB
  int bh = blockIdx.x, tid = threadIdx.x;
  const float* wb = w1 + (size_t)bh*NM*DH;
  for (int i = tid*4; i < NM*DH; i += 1024) *(float4*)&W1s[i] = *(const float4*)&wb[i];
  __syncthreads();
  const float* zr = z + ((size_t)bh*NM + tid)*NM;
  float acc[DH] = {};
  for (int j = 0; j < NM; ++j) {
    float zv = zr[j];
    #pragma unroll
    for (int d = 0; d < DH; ++d) acc[d] = fmaf(zv, W1s[j*DH + d], acc[d]);
  }
  float* ob = w2 + ((size_t)bh*NM + tid)*DH;
  #pragma unroll
  for (int d = 0; d < DH; ++d) ob[d] = acc[d];
}

// ---------------- fused attn1 softmax @ w2 -> outb (bf16) in [b,n,h*64+d] layout
__global__ __launch_bounds__(256) void k_attn1_out(
    const bf16u* __restrict__ q, const float* __restrict__ klm, const float* __restrict__ w2,
    bf16u* __restrict__ outb) {
  __shared__ float Ks[64][68];
  __shared__ float Ws[64][68];
  __shared__ float So[64][68];
  const int nt = blockIdx.x;   // n-tile of 256
  const int bh = blockIdx.y;
  const int b_ = bh >> 3, h_ = bh & 7;
  const int tid = threadIdx.x;
  const int n = nt*256 + tid;
  float qr[DH];
  {
    const uint4* qp = (const uint4*)(q + ((size_t)bh*NSEQ + n)*DH);
    #pragma unroll
    for (int u = 0; u < 8; ++u) unpack8(qp[u], qr + u*8);
  }
  float acc[DH] = {};
  float ssum = 0;
  const int lr = tid >> 2, lc = (tid & 3) << 4;
  for (int j0 = 0; j0 < NM; j0 += 64) {
    const float* kb = klm + ((size_t)bh*NM + j0 + lr)*DH + lc;
    const float* wb = w2 + ((size_t)bh*NM + j0 + lr)*DH + lc;
    #pragma unroll
    for (int u = 0; u < 4; ++u) {
      *(float4*)&Ks[lr][lc + u*4] = *(const float4*)(kb + u*4);
      *(float4*)&Ws[lr][lc + u*4] = *(const float4*)(wb + u*4);
    }
    __syncthreads();
    for (int jj = 0; jj < 64; ++jj) {
      float d0=0,d1=0,d2=0,d3=0;
      #pragma unroll
      for (int d = 0; d < DH; d += 4) {
        d0 = fmaf(qr[d+0], Ks[jj][d+0], d0);
        d1 = fmaf(qr[d+1], Ks[jj][d+1], d1);
        d2 = fmaf(qr[d+2], Ks[jj][d+2], d2);
        d3 = fmaf(qr[d+3], Ks[jj][d+3], d3);
      }
      float p = __expf((d0+d1)+(d2+d3));
      ssum += p;
      #pragma unroll
      for (int d = 0; d < DH; ++d) acc[d] = fmaf(p, Ws[jj][d], acc[d]);
    }
    __syncthreads();
  }
  float inv = 1.0f/ssum;
  const int wgrp = tid >> 6;
  for (int g = 0; g < 4; ++g) {
    if (wgrp == g) {
      #pragma unroll
      for (int d = 0; d < DH; ++d) So[tid & 63][d] = acc[d]*inv;
    }
    __syncthreads();
    int rbase = nt*256 + (g<<6);
    for (int q4i = tid; q4i < 1024; q4i += 256) {
      int r = q4i >> 4, c = (q4i & 15) << 2;
      ushort4 o;
      o.x = f2b(So[r][c+0]); o.y = f2b(So[r][c+1]);
      o.z = f2b(So[r][c+2]); o.w = f2b(So[r][c+3]);
      *(ushort4*)(outb + ((size_t)b_*NSEQ + rbase + r)*DIMC + (h_<<6) + c) = o;
    }
    __syncthreads();
  }
}

// ---------------- depthwise conv residual: outb += conv(v)   (bf16 RMW)
__global__ __launch_bounds__(256) void k_conv_add(
    const bf16u* __restrict__ vmat, const float* __restrict__ wc, bf16u* __restrict__ outb) {
  int gid = blockIdx.x;
  int n4 = gid & (NSEQ/4 - 1);
  int bh = gid / (NSEQ/4);
  int b_ = bh >> 3, h_ = bh & 7;
  int n = n4*4 + (threadIdx.x >> 6);
  int d = threadIdx.x & 63;
  const bf16u* vb = vmat + ((size_t)bh*NSEQ)*DH + d;
  float s = 0;
  #pragma unroll
  for (int t = 0; t < KW; ++t) {
    int nn = n + t - KW/2;
    if (nn >= 0 && nn < NSEQ) s = fmaf(b2f(vb[(size_t)nn*DH]), wc[h_*KW + t], s);
  }
  size_t oi = ((size_t)b_*NSEQ + n)*DIMC + (h_<<6) + d;
  outb[oi] = f2b(b2f(outb[oi]) + s);
}

// ---------------- final GEMM: [32768,512](bf16) @ [512,512] + bias -> d_out (fp32)
__global__ __launch_bounds__(256) void k_gemm_out(
    const bf16u* __restrict__ A, const float* __restrict__ W,
    const float* __restrict__ bias, float* __restrict__ out) {
  __shared__ float As[16][64];
  __shared__ float Bs[16][64];
  const int row0 = blockIdx.x * 64;
  const int col0 = blockIdx.y * 64;
  const int tid = threadIdx.x;
  const int tx = tid & 15, ty = tid >> 4;
  const int ar = tid >> 2, ak = (tid & 3) << 2;
  const int bk = (tid >> 6) << 2, bc = tid & 63;
  float acc[4][4] = {};
  for (int k0 = 0; k0 < DIMC; k0 += 16) {
    uint2 av = *(const uint2*)(A + (size_t)(row0 + ar) * DIMC + k0 + ak);
    As[ak+0][ar] = __uint_as_float(av.x << 16);
    As[ak+1][ar] = __uint_as_float(av.x & 0xffff0000u);
    As[ak+2][ar] = __uint_as_float(av.y << 16);
    As[ak+3][ar] = __uint_as_float(av.y & 0xffff0000u);
    #pragma unroll
    for (int u = 0; u < 4; ++u)
      Bs[bk+u][bc] = W[(size_t)(k0 + bk + u) * DIMC + col0 + bc];
    __syncthreads();
    #pragma unroll
    for (int kk = 0; kk < 16; ++kk) {
      const float4 a = *(const float4*)&As[kk][ty<<2];
      const float4 b = *(const float4*)&Bs[kk][tx<<2];
      const float avr[4] = {a.x,a.y,a.z,a.w};
      const float bvr[4] = {b.x,b.y,b.z,b.w};
      #pragma unroll
      for (int i=0;i<4;++i)
        #pragma unroll
        for (int j=0;j<4;++j) acc[i][j] = fmaf(avr[i], bvr[j], acc[i][j]);
    }
    __syncthreads();
  }
  const float4 bv = *(const float4*)(bias + col0 + (tx<<2));
  #pragma unroll
  for (int i = 0; i < 4; ++i) {
    int gr = row0 + (ty<<2) + i;
    float4 o = make_float4(acc[i][0]+bv.x, acc[i][1]+bv.y, acc[i][2]+bv.z, acc[i][3]+bv.w);
    *(float4*)(out + (size_t)gr*DIMC + col0 + (tx<<2)) = o;
  }
}

extern "C" void kernel_launch(void* const* d_in, const int* in_sizes, int n_in,
                              void* d_out, int out_size, void* d_ws, size_t ws_size,
                              hipStream_t stream) {
  (void)in_sizes; (void)n_in;
  const float* x      = (const float*)d_in[0];
  const float* w_qkv  = (const float*)d_in[1];
  const float* w_out  = (const float*)d_in[2];
  const float* b_out  = (const float*)d_in[3];
  const float* w_conv = (const float*)d_in[4];
  float* out = (float*)d_out;

  const size_t QKV_E  = (size_t)BHN*NSEQ*DH;      // 16,777,216 elems
  const size_t LM_E   = (size_t)BHN*NM*DH;        // 524,288
  const size_t MM_E   = (size_t)BHN*NM*NM;        // 2,097,152

  char* p = (char*)d_ws;
  bf16u* qb   = (bf16u*)p; p += QKV_E * 2;        // 32 MiB
  bf16u* kb   = (bf16u*)p; p += QKV_E * 2;        // 32 MiB (reused as outb)
  bf16u* vb   = (bf16u*)p; p += QKV_E * 2;        // 32 MiB
  float* ql   = (float*)p; p += LM_E * 4;
  float* klm  = (float*)p; p += LM_E * 4;
  float* a2   = (float*)p; p += MM_E * 4;
  float* xz   = (float*)p; p += MM_E * 4;         // fpart aliases xz..t3 after NS
  float* t2   = (float*)p; p += MM_E * 4;
  float* t3   = (float*)p; p += MM_E * 4;
  float* z0   = (float*)p; p += MM_E * 4;
  float* z1   = (float*)p; p += MM_E * 4;
  float* w1   = (float*)p; p += LM_E * 4;
  float* w2   = (float*)p; p += LM_E * 4;
  unsigned* scal = (unsigned*)p; p += 64;
  size_t need = (size_t)(p - (char*)d_ws);

  if (ws_size < need) {
    // Diagnostic: distinguish "workspace too small" from other failures.
    k_fill<<<(out_size + 255)/256, 256, 0, stream>>>(out, out_size, 12345.0f);
    return;
  }

  bf16u* outb = kb;           // kb dead after k_attn3v
  float* fpart = xz;          // xz/t2/t3 dead after NS loop; need 17.0MB <= 24MB

  // 1. qkv projection + head split + q scale (bf16 out)
  k_gemm_qkv<<<dim3((BQ*NSEQ)/64, (3*DIMC)/64), 256, 0, stream>>>(x, w_qkv, qb, kb, vb);
  // 2. landmarks (fp32)
  k_landmarks<<<(BHN*NM)/4, 256, 0, stream>>>(qb, kb, ql, klm);
  // 3. attn2 (fp32)
  k_attn2<<<BHN, 256, 0, stream>>>(ql, klm, a2);
  // 4. pinv init
  k_zero_scal<<<1, 64, 0, stream>>>(scal);
  k_pinv_reduce<<<BHN, 256, 0, stream>>>(a2, scal);
  k_zinit<<<(int)(MM_E/256), 256, 0, stream>>>(a2, scal, z0);
  // 5. Newton-Schulz iterations (fp32)
  float* zc = z0; float* zn = z1;
  for (int it = 0; it < NITER; ++it) {
    k_gemm256<0><<<dim3(16, BHN), 256, 0, stream>>>(a2, zc, xz, 1.0f, 0.0f);
    k_gemm256<1><<<dim3(16, BHN), 256, 0, stream>>>(xz, xz, t2, -1.0f, 15.0f);
    k_gemm256<0><<<dim3(16, BHN), 256, 0, stream>>>(xz, t2, t3, -1.0f, 13.0f);
    k_gemm256<0><<<dim3(16, BHN), 256, 0, stream>>>(zc, t3, zn, 0.25f, 0.0f);
    float* tmp = zc; zc = zn; zn = tmp;
  }
  // 6. w1 = softmax(ql @ k^T) @ v   (fused, sliced; k dead afterwards)
  k_attn3v<<<dim3(NSLICE, BHN), 256, 0, stream>>>(ql, kb, vb, fpart);
  k_attn3v_combine<<<(BHN*NM)/4, 256, 0, stream>>>(fpart, w1);
  // 7. w2 = pinv @ w1
  k_w2<<<BHN, 256, 0, stream>>>(zc, w1, w2);
  // 8. out = softmax(q @ klm^T) @ w2  -> outb bf16 [b,n,h*d]
  k_attn1_out<<<dim3(NSEQ/256, BHN), 256, 0, stream>>>(qb, klm, w2, outb);
  // 9. conv residual
  k_conv_add<<<BHN*NSEQ/4, 256, 0, stream>>>(vb, w_conv, outb);
  // 10. output projection
  k_gemm_out<<<dim3((BQ*NSEQ)/64, DIMC/64), 256, 0, stream>>>(outb, w_out, b_out, out);
}

// Round 3
// 999.548 us; speedup vs baseline: 3.4990x; 3.4990x over previous
//
#include <hip/hip_runtime.h>
#include <cstdint>
#include <cstddef>

#define BQ 4
#define NSEQ 8192
#define DIMC 512
#define NH 8
#define DH 64
#define NM 256
#define NITER 6
#define KW 33
#define BHN (BQ*NH)
#define NSLICE 8

typedef unsigned short bf16u;
typedef __attribute__((ext_vector_type(8))) short short8;
typedef __attribute__((ext_vector_type(4))) float f32x4;
#define MFMA16(a,b,c) __builtin_amdgcn_mfma_f32_16x16x32_bf16(a,b,c,0,0,0)

__device__ inline float b2f(bf16u u) { return __uint_as_float(((unsigned int)u) << 16); }
__device__ inline bf16u f2b(float f) {
  unsigned int u = __float_as_uint(f);
  unsigned int r = (u + 0x7fffu + ((u >> 16) & 1u)) >> 16;  // RNE
  return (bf16u)r;
}

__global__ __launch_bounds__(256) void k_fill(float* out, int n, float v) {
  int i = blockIdx.x * 256 + threadIdx.x;
  if (i < n) out[i] = v;
}

// ---------------- fp32 -> bf16 elementwise (8 per thread)
__global__ __launch_bounds__(256) void c_f2b(const float* __restrict__ src, bf16u* __restrict__ dst, int n8) {
  int i = blockIdx.x*256 + threadIdx.x;
  if (i < n8) {
    const float4* s = (const float4*)(src + (size_t)i*8);
    float4 a = s[0], b = s[1];
    ushort4 lo, hi;
    lo.x=f2b(a.x); lo.y=f2b(a.y); lo.z=f2b(a.z); lo.w=f2b(a.w);
    hi.x=f2b(b.x); hi.y=f2b(b.y); hi.z=f2b(b.z); hi.w=f2b(b.w);
    ushort4* d = (ushort4*)(dst + (size_t)i*8);
    d[0] = lo; d[1] = hi;
  }
}

// ---------------- fp32 [R][C] -> bf16 transposed [C][R]
__global__ __launch_bounds__(256) void c_transb(const float* __restrict__ w, bf16u* __restrict__ wT, int R, int C) {
  int i = blockIdx.x*256 + threadIdx.x;
  if (i < R*C) {
    int r = i / C, c = i - r*C;
    wT[(size_t)c*R + r] = f2b(w[i]);
  }
}

// ---------------- MFMA GEMM  C[M,·] = A[M,K](bf16) @ Bt[N,K]^T(bf16)
// MODE 0: qkv epilogue -> q(scaled)/k bf16 [b,h,n,d], v -> vT bf16 [b,h,d,n]
// MODE 1: out-proj epilogue -> fp32 out += bias
template<int MODE>
__global__ __launch_bounds__(256) void k_mgemm(
    const bf16u* __restrict__ A, const bf16u* __restrict__ Bt, int K,
    bf16u* __restrict__ oq, bf16u* __restrict__ ok, bf16u* __restrict__ ovT,
    const float* __restrict__ bias, float* __restrict__ oC) {
  __shared__ short As[128][72];
  __shared__ short Bs[128][72];
  const int m0 = blockIdx.x*128, n0 = blockIdx.y*128;
  const int t = threadIdx.x;
  const int wid = t>>6, l = t&63, lm = l&15, lg = l>>4;
  const int wr = (wid>>1)*64, wc = (wid&1)*64;
  f32x4 acc[4][4];
  #pragma unroll
  for (int i=0;i<4;++i)
    #pragma unroll
    for (int j=0;j<4;++j) acc[i][j] = (f32x4){0,0,0,0};
  for (int k0=0; k0<K; k0+=64) {
    #pragma unroll
    for (int i=0;i<4;++i) {
      int c = t + i*256;
      int row = c>>3, kc = (c&7)<<3;
      *(uint4*)&As[row][kc] = *(const uint4*)(A  + (size_t)(m0+row)*K + k0+kc);
      *(uint4*)&Bs[row][kc] = *(const uint4*)(Bt + (size_t)(n0+row)*K + k0+kc);
    }
    __syncthreads();
    #pragma unroll
    for (int ks=0;ks<2;++ks) {
      short8 af[4], bfr[4];
      #pragma unroll
      for (int i=0;i<4;++i) {
        af[i]  = *(const short8*)&As[wr+i*16+lm][ks*32+lg*8];
        bfr[i] = *(const short8*)&Bs[wc+i*16+lm][ks*32+lg*8];
      }
      #pragma unroll
      for (int i=0;i<4;++i)
        #pragma unroll
        for (int j=0;j<4;++j)
          acc[i][j] = MFMA16(af[i], bfr[j], acc[i][j]);
    }
    __syncthreads();
  }
  if (MODE==0) {
    #pragma unroll
    for (int mt=0;mt<4;++mt) {
      int grb = m0 + wr + mt*16 + lg*4;     // + r
      int b_ = grb>>13, nrow = grb & (NSEQ-1);
      #pragma unroll
      for (int nt=0;nt<4;++nt) {
        int gc = n0 + wc + nt*16 + lm;
        int which = gc>>9, h_ = (gc>>6)&7, d = gc&63;
        if (which==2) {
          ushort4 pk;
          pk.x=f2b(acc[mt][nt][0]); pk.y=f2b(acc[mt][nt][1]);
          pk.z=f2b(acc[mt][nt][2]); pk.w=f2b(acc[mt][nt][3]);
          *(ushort4*)(ovT + (((size_t)b_*NH+h_)*DH + d)*NSEQ + nrow) = pk;
        } else {
          bf16u* dst = (which==0) ? oq : ok;
          float mul = (which==0) ? 0.125f : 1.0f;
          #pragma unroll
          for (int r=0;r<4;++r)
            dst[(((size_t)b_*NH+h_)*NSEQ + nrow + r)*DH + d] = f2b(acc[mt][nt][r]*mul);
        }
      }
    }
  } else {
    #pragma unroll
    for (int mt=0;mt<4;++mt)
      #pragma unroll
      for (int r=0;r<4;++r) {
        int gr = m0 + wr + mt*16 + lg*4 + r;
        #pragma unroll
        for (int nt=0;nt<4;++nt) {
          int gc = n0 + wc + nt*16 + lm;
          oC[(size_t)gr*DIMC + gc] = acc[mt][nt][r] + bias[gc];
        }
      }
  }
}

// ---------------- landmark means over blocks of 32 (fp32 + bf16 outputs)
__global__ __launch_bounds__(256) void k_landmarks(
    const bf16u* __restrict__ q, const bf16u* __restrict__ kbuf,
    float* __restrict__ ql, float* __restrict__ klm,
    bf16u* __restrict__ qlb, bf16u* __restrict__ klmb) {
  int gi = blockIdx.x*4 + (threadIdx.x>>6);
  int d = threadIdx.x & 63;
  int bh = gi >> 8, i = gi & 255;
  size_t srcoff = ((size_t)bh*NSEQ + (size_t)i*32)*DH + d;
  float sq = 0, sk = 0;
  #pragma unroll
  for (int j = 0; j < 32; ++j) {
    sq += b2f(q[srcoff + (size_t)j*DH]);
    sk += b2f(kbuf[srcoff + (size_t)j*DH]);
  }
  float mq = sq * (1.0f/32.0f), mk = sk * (1.0f/32.0f);
  ql[(size_t)gi*DH + d]  = mq;  klm[(size_t)gi*DH + d]  = mk;
  qlb[(size_t)gi*DH + d] = f2b(mq); klmb[(size_t)gi*DH + d] = f2b(mk);
}

// ---------------- attn2 = softmax(ql @ klm^T), fp32, one WG per bh
__global__ __launch_bounds__(256) void k_attn2(
    const float* __restrict__ ql, const float* __restrict__ klm, float* __restrict__ a2) {
  __shared__ float kls[NM*DH];
  int bh = blockIdx.x, tid = threadIdx.x;
  const float* klb = klm + (size_t)bh*NM*DH;
  for (int i = tid*4; i < NM*DH; i += 1024) *(float4*)&kls[i] = *(const float4*)&klb[i];
  __syncthreads();
  float qr[DH];
  const float* qb = ql + ((size_t)bh*NM + tid)*DH;
  #pragma unroll
  for (int d = 0; d < DH; ++d) qr[d] = qb[d];
  float* arow = a2 + ((size_t)bh*NM + tid)*NM;
  float ssum = 0;
  for (int j = 0; j < NM; ++j) {
    float d0=0,d1=0,d2=0,d3=0;
    #pragma unroll
    for (int d = 0; d < DH; d += 4) {
      d0 = fmaf(qr[d+0], kls[j*DH+d+0], d0);
      d1 = fmaf(qr[d+1], kls[j*DH+d+1], d1);
      d2 = fmaf(qr[d+2], kls[j*DH+d+2], d2);
      d3 = fmaf(qr[d+3], kls[j*DH+d+3], d3);
    }
    float p = __expf((d0+d1)+(d2+d3));
    ssum += p;
    arow[j] = p;
  }
  float inv = 1.0f/ssum;
  for (int j = 0; j < NM; ++j) arow[j] *= inv;
}

// ---------------- pinv init
__global__ void k_zero_scal(unsigned* scal) { if (threadIdx.x < 2) scal[threadIdx.x] = 0u; }

__global__ __launch_bounds__(256) void k_pinv_reduce(const float* __restrict__ a2, unsigned* scal) {
  int bh = blockIdx.x, t = threadIdx.x;
  const float* A = a2 + (size_t)bh*NM*NM;
  float rs = 0, cs = 0;
  for (int j = 0; j < NM; ++j) rs += fabsf(A[(size_t)t*NM + j]);
  for (int i = 0; i < NM; ++i) cs += fabsf(A[(size_t)i*NM + t]);
  __shared__ float red[256];
  red[t] = rs; __syncthreads();
  for (int s = 128; s > 0; s >>= 1) { if (t < s) red[t] = fmaxf(red[t], red[t+s]); __syncthreads(); }
  if (t == 0) atomicMax(scal+0, __float_as_uint(red[0]));
  __syncthreads();
  red[t] = cs; __syncthreads();
  for (int s = 128; s > 0; s >>= 1) { if (t < s) red[t] = fmaxf(red[t], red[t+s]); __syncthreads(); }
  if (t == 0) atomicMax(scal+1, __float_as_uint(red[0]));
}

__global__ __launch_bounds__(256) void k_zinit(
    const float* __restrict__ a2, const unsigned* __restrict__ scal, float* __restrict__ z) {
  size_t idx = (size_t)blockIdx.x*256 + threadIdx.x;
  int bh = (int)(idx >> 16);
  int ij = (int)(idx & 65535);
  int i = ij >> 8, j = ij & 255;
  float denom = __uint_as_float(scal[0]) * __uint_as_float(scal[1]);
  z[idx] = a2[((size_t)bh<<16) + ((size_t)j<<8) + i] / denom;
}

// ---------------- batched 256^3 fp32 GEMM (NS iteration), unchanged
template<int BMODE>
__global__ __launch_bounds__(256) void k_gemm256(
    const float* __restrict__ A, const float* __restrict__ Bm, float* __restrict__ C,
    float alpha, float betaI) {
  __shared__ float As[32][64];
  __shared__ float Bs[32][64];
  const int bh = blockIdx.y;
  const int tm = blockIdx.x & 3, tn = blockIdx.x >> 2;
  const size_t base = (size_t)bh << 16;
  const int row0 = tm*64, col0 = tn*64;
  const int tid = threadIdx.x;
  const int tx = tid & 15, ty = tid >> 4;
  const int ar = tid >> 2, ak = (tid & 3) << 3;
  const int br = tid >> 3, bc0 = (tid & 7) << 3;
  float acc[4][4] = {};
  for (int k0 = 0; k0 < 256; k0 += 32) {
    float4 a0 = *(const float4*)(A + base + (size_t)(row0+ar)*256 + k0 + ak);
    float4 a1 = *(const float4*)(A + base + (size_t)(row0+ar)*256 + k0 + ak + 4);
    As[ak+0][ar]=a0.x; As[ak+1][ar]=a0.y; As[ak+2][ar]=a0.z; As[ak+3][ar]=a0.w;
    As[ak+4][ar]=a1.x; As[ak+5][ar]=a1.y; As[ak+6][ar]=a1.z; As[ak+7][ar]=a1.w;
    float4 b0 = *(const float4*)(Bm + base + (size_t)(k0+br)*256 + col0 + bc0);
    float4 b1 = *(const float4*)(Bm + base + (size_t)(k0+br)*256 + col0 + bc0 + 4);
    if (BMODE == 1) {
      const int kg = k0 + br;
      float bv[8] = {b0.x,b0.y,b0.z,b0.w,b1.x,b1.y,b1.z,b1.w};
      #pragma unroll
      for (int u = 0; u < 8; ++u)
        Bs[br][bc0+u] = ((col0 + bc0 + u) == kg ? 7.0f : 0.0f) - bv[u];
    } else {
      *(float4*)&Bs[br][bc0] = b0;
      *(float4*)&Bs[br][bc0+4] = b1;
    }
    __syncthreads();
    #pragma unroll
    for (int kk = 0; kk < 32; ++kk) {
      const float4 a = *(const float4*)&As[kk][ty<<2];
      const float4 b = *(const float4*)&Bs[kk][tx<<2];
      const float avr[4] = {a.x,a.y,a.z,a.w};
      const float bvr[4] = {b.x,b.y,b.z,b.w};
      #pragma unroll
      for (int i=0;i<4;++i)
        #pragma unroll
        for (int j=0;j<4;++j) acc[i][j] = fmaf(avr[i], bvr[j], acc[i][j]);
    }
    __syncthreads();
  }
  #pragma unroll
  for (int i = 0; i < 4; ++i) {
    int gr = row0 + (ty<<2) + i;
    float o[4];
    #pragma unroll
    for (int j = 0; j < 4; ++j) {
      int gc = col0 + (tx<<2) + j;
      o[j] = alpha*acc[i][j] + ((gr==gc) ? betaI : 0.0f);
    }
    *(float4*)(C + base + (size_t)gr*256 + col0 + (tx<<2)) = make_float4(o[0],o[1],o[2],o[3]);
  }
}

// ---------------- fused MFMA flash attention (no max-subtraction)
// MODE 0 (attn3v): Q = qlb [bh][256][64], K = kb [bh][8192][64], V^T = vT [bh][64][8192]
//                  grid (8 slices, 32 bh) -> fpart partials (acc + rowsum)
// MODE 1 (attn1):  Q = qb [bh][8192][64], K = klmb [bh][256][64], V^T = w2T [bh][64][256]
//                  grid (32 qtiles, 32 bh) -> outb bf16 [b,n,512]
template<int MODE>
__global__ __launch_bounds__(256) void k_flash(
    const bf16u* __restrict__ qg, const bf16u* __restrict__ kg,
    const bf16u* __restrict__ vtg, float* __restrict__ fpart, bf16u* __restrict__ outb) {
  constexpr int NCH = (MODE==0) ? 16 : 4;
  const int bh = blockIdx.y;
  const int tile = blockIdx.x;
  const int t = threadIdx.x;
  const int wid = t>>6, l = t&63, lm = l&15, lg = l>>4;
  const size_t NQbase = (MODE==0) ? ((size_t)bh*NM) : ((size_t)bh*NSEQ + (size_t)tile*256);
  const int NJ = (MODE==0) ? NSEQ : NM;
  const int j0base = (MODE==0) ? tile*1024 : 0;

  __shared__ short Ks[64][72];
  __shared__ short Vs[64][72];
  __shared__ short Pt[4][64][72];

  short8 qf[4][2];
  {
    const bf16u* qrow = qg + (NQbase + (size_t)wid*64) * DH;
    #pragma unroll
    for (int mt=0;mt<4;++mt)
      #pragma unroll
      for (int ks=0;ks<2;++ks)
        qf[mt][ks] = *(const short8*)(qrow + (size_t)(mt*16+lm)*DH + ks*32 + lg*8);
  }
  f32x4 oacc[4][4];
  #pragma unroll
  for (int i=0;i<4;++i)
    #pragma unroll
    for (int j=0;j<4;++j) oacc[i][j] = (f32x4){0,0,0,0};
  float rs[4][4];
  #pragma unroll
  for (int i=0;i<4;++i) { rs[i][0]=0; rs[i][1]=0; rs[i][2]=0; rs[i][3]=0; }

  const bf16u* kbh = kg  + (size_t)bh*NJ*DH;
  const bf16u* vbh = vtg + (size_t)bh*DH*NJ;

  for (int ch=0; ch<NCH; ++ch) {
    int j0 = j0base + ch*64;
    #pragma unroll
    for (int i=0;i<2;++i) {
      int c = t + i*256;
      int row = c>>3, kc = (c&7)<<3;
      *(uint4*)&Ks[row][kc] = *(const uint4*)(kbh + (size_t)(j0+row)*DH + kc);
      *(uint4*)&Vs[row][kc] = *(const uint4*)(vbh + (size_t)row*NJ + j0 + kc);
    }
    __syncthreads();
    short8 kf[4][2];
    #pragma unroll
    for (int jt=0;jt<4;++jt)
      #pragma unroll
      for (int ks=0;ks<2;++ks)
        kf[jt][ks] = *(const short8*)&Ks[jt*16+lm][ks*32+lg*8];
    #pragma unroll
    for (int mt=0;mt<4;++mt) {
      #pragma unroll
      for (int jt=0;jt<4;++jt) {
        f32x4 s = (f32x4){0,0,0,0};
        s = MFMA16(qf[mt][0], kf[jt][0], s);
        s = MFMA16(qf[mt][1], kf[jt][1], s);
        #pragma unroll
        for (int r=0;r<4;++r) {
          float p = __expf(s[r]);
          rs[mt][r] += p;
          Pt[wid][mt*16+lg*4+r][jt*16+lm] = f2b(p);
        }
      }
    }
    short8 vf[4][2];
    #pragma unroll
    for (int dt=0;dt<4;++dt)
      #pragma unroll
      for (int jw=0;jw<2;++jw)
        vf[dt][jw] = *(const short8*)&Vs[dt*16+lm][jw*32+lg*8];
    #pragma unroll
    for (int mt=0;mt<4;++mt) {
      short8 pa0 = *(const short8*)&Pt[wid][mt*16+lm][lg*8];
      short8 pa1 = *(const short8*)&Pt[wid][mt*16+lm][32+lg*8];
      #pragma unroll
      for (int dt=0;dt<4;++dt) {
        oacc[mt][dt] = MFMA16(pa0, vf[dt][0], oacc[mt][dt]);
        oacc[mt][dt] = MFMA16(pa1, vf[dt][1], oacc[mt][dt]);
      }
    }
    __syncthreads();
  }
  #pragma unroll
  for (int mt=0;mt<4;++mt)
    #pragma unroll
    for (int r=0;r<4;++r) {
      float v = rs[mt][r];
      v += __shfl_xor(v, 1); v += __shfl_xor(v, 2);
      v += __shfl_xor(v, 4); v += __shfl_xor(v, 8);
      rs[mt][r] = v;
    }
  if (MODE==0) {
    float* fb = fpart + (((size_t)bh*NSLICE + tile)*NM)*65;
    #pragma unroll
    for (int mt=0;mt<4;++mt)
      #pragma unroll
      for (int r=0;r<4;++r) {
        int row = wid*64 + mt*16 + lg*4 + r;
        float* fr = fb + (size_t)row*65;
        #pragma unroll
        for (int dt=0;dt<4;++dt) fr[dt*16+lm] = oacc[mt][dt][r];
        if (lm==0) fr[64] = rs[mt][r];
      }
  } else {
    const int b_ = bh>>3, h_ = bh&7;
    #pragma unroll
    for (int mt=0;mt<4;++mt)
      #pragma unroll
      for (int r=0;r<4;++r) {
        float inv = 1.0f/rs[mt][r];
        int n = tile*256 + wid*64 + mt*16 + lg*4 + r;
        bf16u* orow = outb + ((size_t)b_*NSEQ + n)*DIMC + h_*DH;
        #pragma unroll
        for (int dt=0;dt<4;++dt)
          orow[dt*16+lm] = f2b(oacc[mt][dt][r]*inv);
      }
  }
}

__global__ __launch_bounds__(256) void k_attn3v_combine(
    const float* __restrict__ fpart, float* __restrict__ w1) {
  int gi = blockIdx.x*4 + (threadIdx.x>>6);
  int d = threadIdx.x & 63;
  int bh = gi >> 8, i = gi & 255;
  float accd = 0, ssum = 0;
  #pragma unroll
  for (int s = 0; s < NSLICE; ++s) {
    const float* fp = fpart + (((size_t)bh*NSLICE + s)*NM + i)*65;
    accd += fp[d];
    ssum += fp[64];
  }
  w1[(size_t)gi*DH + d] = accd / ssum;
}

// ---------------- w2T = (pinv(z) @ w1)^T  bf16 [bh][64][256]
__global__ __launch_bounds__(256) void k_w2(
    const float* __restrict__ z, const float* __restrict__ w1, bf16u* __restrict__ w2T) {
  __shared__ float W1s[NM*DH];
  int bh = blockIdx.x, tid = threadIdx.x;
  const float* wb = w1 + (size_t)bh*NM*DH;
  for (int i = tid*4; i < NM*DH; i += 1024) *(float4*)&W1s[i] = *(const float4*)&wb[i];
  __syncthreads();
  const float* zr = z + ((size_t)bh*NM + tid)*NM;
  float acc[DH] = {};
  for (int j = 0; j < NM; ++j) {
    float zv = zr[j];
    #pragma unroll
    for (int d = 0; d < DH; ++d) acc[d] = fmaf(zv, W1s[j*DH + d], acc[d]);
  }
  bf16u* ob = w2T + (size_t)bh*DH*NM + tid;
  #pragma unroll
  for (int d = 0; d < DH; ++d) ob[(size_t)d*NM] = f2b(acc[d]);
}

// ---------------- depthwise conv residual from vT (contiguous-n reads)
__global__ __launch_bounds__(256) void k_conv_add(
    const bf16u* __restrict__ vt, const float* __restrict__ wc, bf16u* __restrict__ outb) {
  __shared__ short Vs[64][546];
  __shared__ float Wsh[40];
  const int bh = blockIdx.y, nt0 = blockIdx.x*512;
  const int b_ = bh>>3, h_ = bh&7;
  const int t = threadIdx.x;
  if (t < KW) Wsh[t] = wc[h_*KW + t];
  const bf16u* vrow = vt + (size_t)bh*DH*NSEQ;
  for (int c = t; c < 64*68; c += 256) {
    int row = c/68, col8 = (c%68)*8;
    #pragma unroll
    for (int e=0;e<8;++e) {
      int gn = nt0 - 16 + col8 + e;
      Vs[row][col8+e] = (gn>=0 && gn<NSEQ) ? vrow[(size_t)row*NSEQ+gn] : (bf16u)0;
    }
  }
  __syncthreads();
  const int d = t&63, ng = t>>6;
  for (int i=0;i<128;++i) {
    int nl = ng + i*4;
    float s = 0;
    #pragma unroll
    for (int k=0;k<KW;++k) s = fmaf(b2f(Vs[d][nl+k]), Wsh[k], s);
    size_t oi = ((size_t)b_*NSEQ + nt0+nl)*DIMC + h_*DH + d;
    outb[oi] = f2b(b2f(outb[oi]) + s);
  }
}

extern "C" void kernel_launch(void* const* d_in, const int* in_sizes, int n_in,
                              void* d_out, int out_size, void* d_ws, size_t ws_size,
                              hipStream_t stream) {
  (void)in_sizes; (void)n_in;
  const float* x      = (const float*)d_in[0];
  const float* w_qkv  = (const float*)d_in[1];
  const float* w_out  = (const float*)d_in[2];
  const float* b_out  = (const float*)d_in[3];
  const float* w_conv = (const float*)d_in[4];
  float* out = (float*)d_out;

  const size_t QKV_E = (size_t)BHN*NSEQ*DH;   // 16,777,216
  const size_t LM_E  = (size_t)BHN*NM*DH;     // 524,288
  const size_t MM_E  = (size_t)BHN*NM*NM;     // 2,097,152

  char* p = (char*)d_ws;
  bf16u* xb    = (bf16u*)p; p += QKV_E*2*2;   // 64 MiB?? no: xb is 32768x512 = 16,777,216 elems
  // correction: QKV_E == 32768*512, so xb = QKV_E elems * 2B = 32 MiB
  p = (char*)d_ws;
  xb           = (bf16u*)p; p += QKV_E*2;     // 32 MiB ; aliased later by a2/xz/t2/t3
  bf16u* qb    = (bf16u*)p; p += QKV_E*2;     // 32 MiB
  bf16u* kb    = (bf16u*)p; p += QKV_E*2;     // 32 MiB ; aliased later by outb
  bf16u* vT    = (bf16u*)p; p += QKV_E*2;     // 32 MiB
  float* z0    = (float*)p; p += MM_E*4;      // 8 MiB
  float* z1    = (float*)p; p += MM_E*4;      // 8 MiB
  bf16u* wqkvT = (bf16u*)p; p += (size_t)DIMC*3*DIMC*2;  // 1.5 MiB
  bf16u* woutT = (bf16u*)p; p += (size_t)DIMC*DIMC*2;    // 0.5 MiB
  float* ql    = (float*)p; p += LM_E*4;      // 2 MiB
  float* klm   = (float*)p; p += LM_E*4;      // 2 MiB
  bf16u* qlb   = (bf16u*)p; p += LM_E*2;
  bf16u* klmb  = (bf16u*)p; p += LM_E*2;
  float* w1    = (float*)p; p += LM_E*4;      // 2 MiB
  bf16u* w2T   = (bf16u*)p; p += LM_E*2;      // 1 MiB
  unsigned* scal = (unsigned*)p; p += 64;
  size_t need = (size_t)(p - (char*)d_ws);

  if (ws_size < need) {
    k_fill<<<(out_size + 255)/256, 256, 0, stream>>>(out, out_size, 12345.0f);
    return;
  }

  // aliases (liveness-checked):
  float* a2 = (float*)xb;           // xb dead after qkv GEMM
  float* xz = a2 + MM_E;
  float* t2 = xz + MM_E;
  float* t3 = t2 + MM_E;
  float* fpart = xz;                // NS temps dead after NS loop (17 MiB <= 24 MiB)
  bf16u* outb = kb;                 // kb dead after k_flash<0>

  // 1. converts
  c_f2b<<<(int)(QKV_E/8/256), 256, 0, stream>>>(x, xb, (int)(QKV_E/8));
  c_transb<<<(DIMC*3*DIMC+255)/256, 256, 0, stream>>>(w_qkv, wqkvT, DIMC, 3*DIMC);
  c_transb<<<(DIMC*DIMC+255)/256, 256, 0, stream>>>(w_out, woutT, DIMC, DIMC);
  // 2. qkv projection (MFMA)
  k_mgemm<0><<<dim3(256, 12), 256, 0, stream>>>(xb, wqkvT, DIMC, qb, kb, vT, nullptr, nullptr);
  // 3. landmarks
  k_landmarks<<<(BHN*NM)/4, 256, 0, stream>>>(qb, kb, ql, klm, qlb, klmb);
  // 4. attn2 + pinv init (fp32)
  k_attn2<<<BHN, 256, 0, stream>>>(ql, klm, a2);
  k_zero_scal<<<1, 64, 0, stream>>>(scal);
  k_pinv_reduce<<<BHN, 256, 0, stream>>>(a2, scal);
  k_zinit<<<(int)(MM_E/256), 256, 0, stream>>>(a2, scal, z0);
  // 5. Newton-Schulz (fp32)
  float* zc = z0; float* zn = z1;
  for (int it = 0; it < NITER; ++it) {
    k_gemm256<0><<<dim3(16, BHN), 256, 0, stream>>>(a2, zc, xz, 1.0f, 0.0f);
    k_gemm256<1><<<dim3(16, BHN), 256, 0, stream>>>(xz, xz, t2, -1.0f, 15.0f);
    k_gemm256<0><<<dim3(16, BHN), 256, 0, stream>>>(xz, t2, t3, -1.0f, 13.0f);
    k_gemm256<0><<<dim3(16, BHN), 256, 0, stream>>>(zc, t3, zn, 0.25f, 0.0f);
    float* tmp = zc; zc = zn; zn = tmp;
  }
  // 6. w1 = softmax(ql@k^T)@v (MFMA flash, sliced)
  k_flash<0><<<dim3(NSLICE, BHN), 256, 0, stream>>>(qlb, kb, vT, fpart, nullptr);
  k_attn3v_combine<<<(BHN*NM)/4, 256, 0, stream>>>(fpart, w1);
  // 7. w2T = (pinv @ w1)^T
  k_w2<<<BHN, 256, 0, stream>>>(zc, w1, w2T);
  // 8. attn1 @ w2 -> outb (MFMA flash)
  k_flash<1><<<dim3(NSEQ/256, BHN), 256, 0, stream>>>(qb, klmb, w2T, nullptr, outb);
  // 9. conv residual from vT
  k_conv_add<<<dim3(NSEQ/512, BHN), 256, 0, stream>>>(vT, w_conv, outb);
  // 10. output projection (MFMA)
  k_mgemm<1><<<dim3(256, 4), 256, 0, stream>>>(outb, woutT, DIMC, nullptr, nullptr, nullptr, b_out, out);
}

// Round 4
// 825.901 us; speedup vs baseline: 4.2347x; 1.2103x over previous
//
#include <hip/hip_runtime.h>
#include <cstdint>
#include <cstddef>

#define BQ 4
#define NSEQ 8192
#define DIMC 512
#define NH 8
#define DH 64
#define NM 256
#define NITER 6
#define KW 33
#define BHN (BQ*NH)
#define NSLICE 8

typedef unsigned short bf16u;
typedef __attribute__((ext_vector_type(8))) short short8;
typedef __attribute__((ext_vector_type(4))) float f32x4;
#define MFMA16(a,b,c) __builtin_amdgcn_mfma_f32_16x16x32_bf16(a,b,c,0,0,0)

__device__ inline float b2f(bf16u u) { return __uint_as_float(((unsigned int)u) << 16); }
__device__ inline bf16u f2b(float f) {
  unsigned int u = __float_as_uint(f);
  unsigned int r = (u + 0x7fffu + ((u >> 16) & 1u)) >> 16;  // RNE
  return (bf16u)r;
}
// truncation split: v = hi + lo + O(2^-16 |v|)
__device__ inline void splt(float v, unsigned short& h, unsigned short& l) {
  unsigned u = __float_as_uint(v);
  h = (unsigned short)(u >> 16);
  float hf = __uint_as_float(u & 0xffff0000u);
  l = (unsigned short)(__float_as_uint(v - hf) >> 16);
}

__global__ __launch_bounds__(256) void k_fill(float* out, int n, float v) {
  int i = blockIdx.x * 256 + threadIdx.x;
  if (i < n) out[i] = v;
}

// ---------------- fp32 -> bf16 elementwise (8 per thread)
__global__ __launch_bounds__(256) void c_f2b(const float* __restrict__ src, bf16u* __restrict__ dst, int n8) {
  int i = blockIdx.x*256 + threadIdx.x;
  if (i < n8) {
    const float4* s = (const float4*)(src + (size_t)i*8);
    float4 a = s[0], b = s[1];
    ushort4 lo, hi;
    lo.x=f2b(a.x); lo.y=f2b(a.y); lo.z=f2b(a.z); lo.w=f2b(a.w);
    hi.x=f2b(b.x); hi.y=f2b(b.y); hi.z=f2b(b.z); hi.w=f2b(b.w);
    ushort4* d = (ushort4*)(dst + (size_t)i*8);
    d[0] = lo; d[1] = hi;
  }
}

// ---------------- fp32 [R][C] -> bf16 transposed [C][R]
__global__ __launch_bounds__(256) void c_transb(const float* __restrict__ w, bf16u* __restrict__ wT, int R, int C) {
  int i = blockIdx.x*256 + threadIdx.x;
  if (i < R*C) {
    int r = i / C, c = i - r*C;
    wT[(size_t)c*R + r] = f2b(w[i]);
  }
}

// ---------------- MFMA GEMM  C[M,-] = A[M,K](bf16) @ Bt[N,K]^T(bf16)
template<int MODE>
__global__ __launch_bounds__(256) void k_mgemm(
    const bf16u* __restrict__ A, const bf16u* __restrict__ Bt, int K,
    bf16u* __restrict__ oq, bf16u* __restrict__ ok, bf16u* __restrict__ ovT,
    const float* __restrict__ bias, float* __restrict__ oC) {
  __shared__ short As[128][72];
  __shared__ short Bs[128][72];
  const int m0 = blockIdx.x*128, n0 = blockIdx.y*128;
  const int t = threadIdx.x;
  const int wid = t>>6, l = t&63, lm = l&15, lg = l>>4;
  const int wr = (wid>>1)*64, wc = (wid&1)*64;
  f32x4 acc[4][4];
  #pragma unroll
  for (int i=0;i<4;++i)
    #pragma unroll
    for (int j=0;j<4;++j) acc[i][j] = (f32x4){0,0,0,0};
  for (int k0=0; k0<K; k0+=64) {
    #pragma unroll
    for (int i=0;i<4;++i) {
      int c = t + i*256;
      int row = c>>3, kc = (c&7)<<3;
      *(uint4*)&As[row][kc] = *(const uint4*)(A  + (size_t)(m0+row)*K + k0+kc);
      *(uint4*)&Bs[row][kc] = *(const uint4*)(Bt + (size_t)(n0+row)*K + k0+kc);
    }
    __syncthreads();
    #pragma unroll
    for (int ks=0;ks<2;++ks) {
      short8 af[4], bfr[4];
      #pragma unroll
      for (int i=0;i<4;++i) {
        af[i]  = *(const short8*)&As[wr+i*16+lm][ks*32+lg*8];
        bfr[i] = *(const short8*)&Bs[wc+i*16+lm][ks*32+lg*8];
      }
      #pragma unroll
      for (int i=0;i<4;++i)
        #pragma unroll
        for (int j=0;j<4;++j)
          acc[i][j] = MFMA16(af[i], bfr[j], acc[i][j]);
    }
    __syncthreads();
  }
  if (MODE==0) {
    #pragma unroll
    for (int mt=0;mt<4;++mt) {
      int grb = m0 + wr + mt*16 + lg*4;
      int b_ = grb>>13, nrow = grb & (NSEQ-1);
      #pragma unroll
      for (int nt=0;nt<4;++nt) {
        int gc = n0 + wc + nt*16 + lm;
        int which = gc>>9, h_ = (gc>>6)&7, d = gc&63;
        if (which==2) {
          ushort4 pk;
          pk.x=f2b(acc[mt][nt][0]); pk.y=f2b(acc[mt][nt][1]);
          pk.z=f2b(acc[mt][nt][2]); pk.w=f2b(acc[mt][nt][3]);
          *(ushort4*)(ovT + (((size_t)b_*NH+h_)*DH + d)*NSEQ + nrow) = pk;
        } else {
          bf16u* dst = (which==0) ? oq : ok;
          float mul = (which==0) ? 0.125f : 1.0f;
          #pragma unroll
          for (int r=0;r<4;++r)
            dst[(((size_t)b_*NH+h_)*NSEQ + nrow + r)*DH + d] = f2b(acc[mt][nt][r]*mul);
        }
      }
    }
  } else {
    #pragma unroll
    for (int mt=0;mt<4;++mt)
      #pragma unroll
      for (int r=0;r<4;++r) {
        int gr = m0 + wr + mt*16 + lg*4 + r;
        #pragma unroll
        for (int nt=0;nt<4;++nt) {
          int gc = n0 + wc + nt*16 + lm;
          oC[(size_t)gr*DIMC + gc] = acc[mt][nt][r] + bias[gc];
        }
      }
  }
}

// ---------------- landmark means over blocks of 32
__global__ __launch_bounds__(256) void k_landmarks(
    const bf16u* __restrict__ q, const bf16u* __restrict__ kbuf,
    float* __restrict__ ql, float* __restrict__ klm,
    bf16u* __restrict__ qlb, bf16u* __restrict__ klmb) {
  int gi = blockIdx.x*4 + (threadIdx.x>>6);
  int d = threadIdx.x & 63;
  int bh = gi >> 8, i = gi & 255;
  size_t srcoff = ((size_t)bh*NSEQ + (size_t)i*32)*DH + d;
  float sq = 0, sk = 0;
  #pragma unroll
  for (int j = 0; j < 32; ++j) {
    sq += b2f(q[srcoff + (size_t)j*DH]);
    sk += b2f(kbuf[srcoff + (size_t)j*DH]);
  }
  float mq = sq * (1.0f/32.0f), mk = sk * (1.0f/32.0f);
  ql[(size_t)gi*DH + d]  = mq;  klm[(size_t)gi*DH + d]  = mk;
  qlb[(size_t)gi*DH + d] = f2b(mq); klmb[(size_t)gi*DH + d] = f2b(mk);
}

// ---------------- split-bf16 MFMA "NAT" GEMM: C[256][256] = A[256][K] @ S[256][K]^T
// (S symmetric in all uses, so this equals A@S). fp32-equivalent accuracy via hi/lo split.
// BCOMB=1: S-operand is (15I - 7*Sw + S) built on load.
// EPI: 0 plain; 1 scale by 1/(scal0*scal1); 2 C=3.25*E1-0.25*acc; 4 C=exp(acc)
template<int BCOMB, int EPI>
__global__ __launch_bounds__(256) void k_nat(
    const float* __restrict__ A, const float* __restrict__ S, const float* __restrict__ Sw,
    const float* __restrict__ E1, const unsigned* __restrict__ scal,
    float* __restrict__ C, int K) {
  __shared__ short Ah[128][40], Al[128][40], Bh[64][40], Bl[64][40];
  const int bh = blockIdx.y;
  const size_t abase = (size_t)bh*256*K;
  const size_t cbase = (size_t)bh<<16;
  const int m0 = (blockIdx.x & 1)*128, n0 = (blockIdx.x >> 1)*64;
  const int t = threadIdx.x;
  const int wid = t>>6, l = t&63, lm = l&15, lg = l>>4;
  const int wr = (wid&1)*64, wc = (wid>>1)*32;
  f32x4 acc[4][2];
  #pragma unroll
  for (int i=0;i<4;++i) { acc[i][0] = (f32x4){0,0,0,0}; acc[i][1] = (f32x4){0,0,0,0}; }
  for (int k0=0; k0<K; k0+=32) {
    #pragma unroll
    for (int i=0;i<4;++i) {                      // A tile 128x32
      int idx = t + i*256;
      int row = idx>>3, kc = (idx&7)<<2;
      float4 v = *(const float4*)(A + abase + (size_t)(m0+row)*K + k0+kc);
      ushort4 hh, ll;
      splt(v.x, hh.x, ll.x); splt(v.y, hh.y, ll.y);
      splt(v.z, hh.z, ll.z); splt(v.w, hh.w, ll.w);
      *(ushort4*)&Ah[row][kc] = hh; *(ushort4*)&Al[row][kc] = ll;
    }
    #pragma unroll
    for (int i=0;i<2;++i) {                      // S tile 64x32
      int idx = t + i*256;
      int row = idx>>3, kc = (idx&7)<<2;
      float4 v = *(const float4*)(S + abase + (size_t)(n0+row)*K + k0+kc);
      if (BCOMB) {
        float4 w4 = *(const float4*)(Sw + abase + (size_t)(n0+row)*K + k0+kc);
        int gn = n0+row;
        v.x = ((gn==k0+kc+0)?15.0f:0.0f) - 7.0f*w4.x + v.x;
        v.y = ((gn==k0+kc+1)?15.0f:0.0f) - 7.0f*w4.y + v.y;
        v.z = ((gn==k0+kc+2)?15.0f:0.0f) - 7.0f*w4.z + v.z;
        v.w = ((gn==k0+kc+3)?15.0f:0.0f) - 7.0f*w4.w + v.w;
      }
      ushort4 hh, ll;
      splt(v.x, hh.x, ll.x); splt(v.y, hh.y, ll.y);
      splt(v.z, hh.z, ll.z); splt(v.w, hh.w, ll.w);
      *(ushort4*)&Bh[row][kc] = hh; *(ushort4*)&Bl[row][kc] = ll;
    }
    __syncthreads();
    short8 ah[4], al[4], sh[2], sl[2];
    #pragma unroll
    for (int mt=0;mt<4;++mt) {
      ah[mt] = *(const short8*)&Ah[wr+mt*16+lm][lg*8];
      al[mt] = *(const short8*)&Al[wr+mt*16+lm][lg*8];
    }
    #pragma unroll
    for (int nt=0;nt<2;++nt) {
      sh[nt] = *(const short8*)&Bh[wc+nt*16+lm][lg*8];
      sl[nt] = *(const short8*)&Bl[wc+nt*16+lm][lg*8];
    }
    #pragma unroll
    for (int mt=0;mt<4;++mt)
      #pragma unroll
      for (int nt=0;nt<2;++nt) {
        acc[mt][nt] = MFMA16(ah[mt], sh[nt], acc[mt][nt]);
        acc[mt][nt] = MFMA16(ah[mt], sl[nt], acc[mt][nt]);
        acc[mt][nt] = MFMA16(al[mt], sh[nt], acc[mt][nt]);
      }
    __syncthreads();
  }
  float rc = 1.0f;
  if (EPI==1) rc = 1.0f/(__uint_as_float(scal[0]) * __uint_as_float(scal[1]));
  #pragma unroll
  for (int mt=0;mt<4;++mt)
    #pragma unroll
    for (int nt=0;nt<2;++nt)
      #pragma unroll
      for (int r=0;r<4;++r) {
        int gr = m0 + wr + mt*16 + lg*4 + r;
        int gc = n0 + wc + nt*16 + lm;
        size_t idx = cbase + (size_t)gr*256 + gc;
        float a = acc[mt][nt][r];
        if (EPI==0) C[idx] = a;
        else if (EPI==1) C[idx] = a*rc;
        else if (EPI==2) C[idx] = 3.25f*E1[idx] - 0.25f*a;
        else if (EPI==4) C[idx] = __expf(a);
      }
}

// ---------------- w2T[bh][64][256] = NAT(w1T, Z) = w1^T @ Z^T(=z@w1 transposed), bf16 out
__global__ __launch_bounds__(256) void k_w2nat(
    const float* __restrict__ w1T, const float* __restrict__ Z, bf16u* __restrict__ w2T) {
  __shared__ short Ah[64][40], Al[64][40], Bh[64][40], Bl[64][40];
  const int bh = blockIdx.y;
  const int n0 = blockIdx.x*64;
  const size_t a0 = (size_t)bh*64*256;
  const size_t s0 = (size_t)bh<<16;
  const int t = threadIdx.x;
  const int wid = t>>6, l = t&63, lm = l&15, lg = l>>4;
  const int wc = wid*16;
  f32x4 acc[4];
  #pragma unroll
  for (int i=0;i<4;++i) acc[i] = (f32x4){0,0,0,0};
  for (int k0=0; k0<256; k0+=32) {
    #pragma unroll
    for (int i=0;i<2;++i) {
      int idx = t + i*256;
      int row = idx>>3, kc = (idx&7)<<2;
      float4 v = *(const float4*)(w1T + a0 + (size_t)row*256 + k0+kc);
      ushort4 hh, ll;
      splt(v.x, hh.x, ll.x); splt(v.y, hh.y, ll.y);
      splt(v.z, hh.z, ll.z); splt(v.w, hh.w, ll.w);
      *(ushort4*)&Ah[row][kc] = hh; *(ushort4*)&Al[row][kc] = ll;
      float4 u = *(const float4*)(Z + s0 + (size_t)(n0+row)*256 + k0+kc);
      splt(u.x, hh.x, ll.x); splt(u.y, hh.y, ll.y);
      splt(u.z, hh.z, ll.z); splt(u.w, hh.w, ll.w);
      *(ushort4*)&Bh[row][kc] = hh; *(ushort4*)&Bl[row][kc] = ll;
    }
    __syncthreads();
    short8 sh = *(const short8*)&Bh[wc+lm][lg*8];
    short8 sl = *(const short8*)&Bl[wc+lm][lg*8];
    #pragma unroll
    for (int mt=0;mt<4;++mt) {
      short8 ah = *(const short8*)&Ah[mt*16+lm][lg*8];
      short8 al = *(const short8*)&Al[mt*16+lm][lg*8];
      acc[mt] = MFMA16(ah, sh, acc[mt]);
      acc[mt] = MFMA16(ah, sl, acc[mt]);
      acc[mt] = MFMA16(al, sh, acc[mt]);
    }
    __syncthreads();
  }
  #pragma unroll
  for (int mt=0;mt<4;++mt)
    #pragma unroll
    for (int r=0;r<4;++r) {
      int gm = mt*16 + lg*4 + r;
      w2T[a0 + (size_t)gm*256 + n0 + wc + lm] = f2b(acc[mt][r]);
    }
}

// ---------------- row softmax-normalize (a2 holds exp(logits))
__global__ __launch_bounds__(256) void k_rowsm(float* __restrict__ a2) {
  int row = blockIdx.x*4 + (threadIdx.x>>6);
  int l = threadIdx.x & 63;
  float4* p = (float4*)(a2 + (size_t)row*256 + l*4);
  float4 v = *p;
  float s = v.x+v.y+v.z+v.w;
  #pragma unroll
  for (int d=1; d<64; d<<=1) s += __shfl_xor(s, d);
  float inv = 1.0f/s;
  v.x*=inv; v.y*=inv; v.z*=inv; v.w*=inv;
  *p = v;
}

// ---------------- pinv init
__global__ void k_zero_scal(unsigned* scal) { if (threadIdx.x < 2) scal[threadIdx.x] = 0u; }

__global__ __launch_bounds__(256) void k_pinv_reduce(const float* __restrict__ a2, unsigned* scal) {
  int bh = blockIdx.x, t = threadIdx.x;
  const float* A = a2 + (size_t)bh*NM*NM;
  float rs = 0, cs = 0;
  for (int j = 0; j < NM; ++j) rs += fabsf(A[(size_t)t*NM + j]);
  for (int i = 0; i < NM; ++i) cs += fabsf(A[(size_t)i*NM + t]);
  __shared__ float red[256];
  red[t] = rs; __syncthreads();
  for (int s = 128; s > 0; s >>= 1) { if (t < s) red[t] = fmaxf(red[t], red[t+s]); __syncthreads(); }
  if (t == 0) atomicMax(scal+0, __float_as_uint(red[0]));
  __syncthreads();
  red[t] = cs; __syncthreads();
  for (int s = 128; s > 0; s >>= 1) { if (t < s) red[t] = fmaxf(red[t], red[t+s]); __syncthreads(); }
  if (t == 0) atomicMax(scal+1, __float_as_uint(red[0]));
}

__global__ __launch_bounds__(256) void k_zinit(
    const float* __restrict__ a2, const unsigned* __restrict__ scal, float* __restrict__ z) {
  size_t idx = (size_t)blockIdx.x*256 + threadIdx.x;
  int bh = (int)(idx >> 16);
  int ij = (int)(idx & 65535);
  int i = ij >> 8, j = ij & 255;
  float denom = __uint_as_float(scal[0]) * __uint_as_float(scal[1]);
  z[idx] = a2[((size_t)bh<<16) + ((size_t)j<<8) + i] / denom;
}

// ---------------- fused MFMA flash attention (no max-subtraction)
template<int MODE>
__global__ __launch_bounds__(256) void k_flash(
    const bf16u* __restrict__ qg, const bf16u* __restrict__ kg,
    const bf16u* __restrict__ vtg, float* __restrict__ fpart, bf16u* __restrict__ outb) {
  constexpr int NCH = (MODE==0) ? 16 : 4;
  const int bh = blockIdx.y;
  const int tile = blockIdx.x;
  const int t = threadIdx.x;
  const int wid = t>>6, l = t&63, lm = l&15, lg = l>>4;
  const size_t NQbase = (MODE==0) ? ((size_t)bh*NM) : ((size_t)bh*NSEQ + (size_t)tile*256);
  const int NJ = (MODE==0) ? NSEQ : NM;
  const int j0base = (MODE==0) ? tile*1024 : 0;

  __shared__ short Ks[64][72];
  __shared__ short Vs[64][72];
  __shared__ short Pt[4][64][72];

  short8 qf[4][2];
  {
    const bf16u* qrow = qg + (NQbase + (size_t)wid*64) * DH;
    #pragma unroll
    for (int mt=0;mt<4;++mt)
      #pragma unroll
      for (int ks=0;ks<2;++ks)
        qf[mt][ks] = *(const short8*)(qrow + (size_t)(mt*16+lm)*DH + ks*32 + lg*8);
  }
  f32x4 oacc[4][4];
  #pragma unroll
  for (int i=0;i<4;++i)
    #pragma unroll
    for (int j=0;j<4;++j) oacc[i][j] = (f32x4){0,0,0,0};
  float rs[4][4];
  #pragma unroll
  for (int i=0;i<4;++i) { rs[i][0]=0; rs[i][1]=0; rs[i][2]=0; rs[i][3]=0; }

  const bf16u* kbh = kg  + (size_t)bh*NJ*DH;
  const bf16u* vbh = vtg + (size_t)bh*DH*NJ;

  for (int ch=0; ch<NCH; ++ch) {
    int j0 = j0base + ch*64;
    #pragma unroll
    for (int i=0;i<2;++i) {
      int c = t + i*256;
      int row = c>>3, kc = (c&7)<<3;
      *(uint4*)&Ks[row][kc] = *(const uint4*)(kbh + (size_t)(j0+row)*DH + kc);
      *(uint4*)&Vs[row][kc] = *(const uint4*)(vbh + (size_t)row*NJ + j0 + kc);
    }
    __syncthreads();
    short8 kf[4][2];
    #pragma unroll
    for (int jt=0;jt<4;++jt)
      #pragma unroll
      for (int ks=0;ks<2;++ks)
        kf[jt][ks] = *(const short8*)&Ks[jt*16+lm][ks*32+lg*8];
    #pragma unroll
    for (int mt=0;mt<4;++mt) {
      #pragma unroll
      for (int jt=0;jt<4;++jt) {
        f32x4 s = (f32x4){0,0,0,0};
        s = MFMA16(qf[mt][0], kf[jt][0], s);
        s = MFMA16(qf[mt][1], kf[jt][1], s);
        #pragma unroll
        for (int r=0;r<4;++r) {
          float p = __expf(s[r]);
          rs[mt][r] += p;
          Pt[wid][mt*16+lg*4+r][jt*16+lm] = f2b(p);
        }
      }
    }
    short8 vf[4][2];
    #pragma unroll
    for (int dt=0;dt<4;++dt)
      #pragma unroll
      for (int jw=0;jw<2;++jw)
        vf[dt][jw] = *(const short8*)&Vs[dt*16+lm][jw*32+lg*8];
    #pragma unroll
    for (int mt=0;mt<4;++mt) {
      short8 pa0 = *(const short8*)&Pt[wid][mt*16+lm][lg*8];
      short8 pa1 = *(const short8*)&Pt[wid][mt*16+lm][32+lg*8];
      #pragma unroll
      for (int dt=0;dt<4;++dt) {
        oacc[mt][dt] = MFMA16(pa0, vf[dt][0], oacc[mt][dt]);
        oacc[mt][dt] = MFMA16(pa1, vf[dt][1], oacc[mt][dt]);
      }
    }
    __syncthreads();
  }
  #pragma unroll
  for (int mt=0;mt<4;++mt)
    #pragma unroll
    for (int r=0;r<4;++r) {
      float v = rs[mt][r];
      v += __shfl_xor(v, 1); v += __shfl_xor(v, 2);
      v += __shfl_xor(v, 4); v += __shfl_xor(v, 8);
      rs[mt][r] = v;
    }
  if (MODE==0) {
    float* fb = fpart + (((size_t)bh*NSLICE + tile)*NM)*65;
    #pragma unroll
    for (int mt=0;mt<4;++mt)
      #pragma unroll
      for (int r=0;r<4;++r) {
        int row = wid*64 + mt*16 + lg*4 + r;
        float* fr = fb + (size_t)row*65;
        #pragma unroll
        for (int dt=0;dt<4;++dt) fr[dt*16+lm] = oacc[mt][dt][r];
        if (lm==0) fr[64] = rs[mt][r];
      }
  } else {
    const int b_ = bh>>3, h_ = bh&7;
    #pragma unroll
    for (int mt=0;mt<4;++mt)
      #pragma unroll
      for (int r=0;r<4;++r) {
        float inv = 1.0f/rs[mt][r];
        int n = tile*256 + wid*64 + mt*16 + lg*4 + r;
        bf16u* orow = outb + ((size_t)b_*NSEQ + n)*DIMC + h_*DH;
        #pragma unroll
        for (int dt=0;dt<4;++dt)
          orow[dt*16+lm] = f2b(oacc[mt][dt][r]*inv);
      }
  }
}

// combine -> w1T fp32 [bh][64][256]
__global__ __launch_bounds__(256) void k_attn3v_combine(
    const float* __restrict__ fpart, float* __restrict__ w1T) {
  int gi = blockIdx.x*4 + (threadIdx.x>>6);
  int d = threadIdx.x & 63;
  int bh = gi >> 8, i = gi & 255;
  float accd = 0, ssum = 0;
  #pragma unroll
  for (int s = 0; s < NSLICE; ++s) {
    const float* fp = fpart + (((size_t)bh*NSLICE + s)*NM + i)*65;
    accd += fp[d];
    ssum += fp[64];
  }
  w1T[((size_t)bh*64 + d)*256 + i] = accd / ssum;
}

// ---------------- depthwise conv residual from vT, LDS-transposed staging
__global__ __launch_bounds__(256) void k_conv_add(
    const bf16u* __restrict__ vt, const float* __restrict__ wc, bf16u* __restrict__ outb) {
  __shared__ short Vs[288][72];
  __shared__ float Wsh[40];
  const int bh = blockIdx.y, n0 = blockIdx.x*256;
  const int b_ = bh>>3, h_ = bh&7;
  const int t = threadIdx.x;
  if (t < KW) Wsh[t] = wc[h_*KW + t];
  const bf16u* vrow = vt + (size_t)bh*DH*NSEQ;
  {
    int d = t&63, seg = t>>6;
    #pragma unroll
    for (int u=0; u<9; ++u) {
      int nl = seg*72 + u*8;
      int gn = n0 - 16 + nl;
      bf16u e8[8];
      if (gn >= 0 && gn + 8 <= NSEQ) {
        *(uint4*)e8 = *(const uint4*)(vrow + (size_t)d*NSEQ + gn);
      } else {
        #pragma unroll
        for (int e=0;e<8;++e) {
          int g = gn + e;
          e8[e] = (g>=0 && g<NSEQ) ? vrow[(size_t)d*NSEQ + g] : (bf16u)0;
        }
      }
      #pragma unroll
      for (int e=0;e<8;++e) Vs[nl+e][d] = e8[e];
    }
  }
  __syncthreads();
  const int d = t&63, q = t>>6;
  #pragma unroll
  for (int c2=0;c2<4;++c2) {
    int nb = q*64 + c2*16;
    float wv[48];
    #pragma unroll
    for (int i=0;i<48;++i) wv[i] = b2f(Vs[nb+i][d]);
    #pragma unroll
    for (int e=0;e<16;++e) {
      float s = 0;
      #pragma unroll
      for (int k=0;k<KW;++k) s = fmaf(wv[e+k], Wsh[k], s);
      size_t oi = ((size_t)b_*NSEQ + n0 + nb + e)*DIMC + h_*DH + d;
      outb[oi] = f2b(b2f(outb[oi]) + s);
    }
  }
}

extern "C" void kernel_launch(void* const* d_in, const int* in_sizes, int n_in,
                              void* d_out, int out_size, void* d_ws, size_t ws_size,
                              hipStream_t stream) {
  (void)in_sizes; (void)n_in;
  const float* x      = (const float*)d_in[0];
  const float* w_qkv  = (const float*)d_in[1];
  const float* w_out  = (const float*)d_in[2];
  const float* b_out  = (const float*)d_in[3];
  const float* w_conv = (const float*)d_in[4];
  float* out = (float*)d_out;

  const size_t QKV_E = (size_t)BHN*NSEQ*DH;   // 16,777,216
  const size_t LM_E  = (size_t)BHN*NM*DH;     // 524,288
  const size_t MM_E  = (size_t)BHN*NM*NM;     // 2,097,152

  char* p = (char*)d_ws;
  char* regionA = p;       p += 4*MM_E*4;     // 32 MiB: xb | {a2/c1, w, wn, s1} | fpart
  bf16u* qb    = (bf16u*)p; p += QKV_E*2;     // 32
  bf16u* kb    = (bf16u*)p; p += QKV_E*2;     // 32 (-> outb)
  bf16u* vT    = (bf16u*)p; p += QKV_E*2;     // 32
  float* zbuf  = (float*)p; p += MM_E*4;      // 8
  float* znbuf = (float*)p; p += MM_E*4;      // 8
  bf16u* wqkvT = (bf16u*)p; p += (size_t)DIMC*3*DIMC*2;
  bf16u* woutT = (bf16u*)p; p += (size_t)DIMC*DIMC*2;
  float* ql    = (float*)p; p += LM_E*4;
  float* klm   = (float*)p; p += LM_E*4;
  bf16u* qlb   = (bf16u*)p; p += LM_E*2;
  bf16u* klmb  = (bf16u*)p; p += LM_E*2;
  float* w1T   = (float*)p; p += LM_E*4;
  bf16u* w2T   = (bf16u*)p; p += LM_E*2;
  unsigned* scal = (unsigned*)p; p += 256;
  size_t need = (size_t)(p - (char*)d_ws);

  if (ws_size < need) {
    k_fill<<<(out_size + 255)/256, 256, 0, stream>>>(out, out_size, 12345.0f);
    return;
  }

  bf16u* xb   = (bf16u*)regionA;
  float* a2   = (float*)regionA;              // after xb dead
  float* wb   = a2 + MM_E;
  float* wnb  = wb + MM_E;
  float* s1   = wnb + MM_E;
  float* c1   = a2;                           // after a2 dead (post w0)
  float* fpart = (float*)regionA;             // after NS chain dead
  bf16u* outb = kb;                           // after flash<0>

  // 1. converts
  c_f2b<<<(int)(QKV_E/8/256), 256, 0, stream>>>(x, xb, (int)(QKV_E/8));
  c_transb<<<(DIMC*3*DIMC+255)/256, 256, 0, stream>>>(w_qkv, wqkvT, DIMC, 3*DIMC);
  c_transb<<<(DIMC*DIMC+255)/256, 256, 0, stream>>>(w_out, woutT, DIMC, DIMC);
  // 2. qkv projection (MFMA)
  k_mgemm<0><<<dim3(256, 12), 256, 0, stream>>>(xb, wqkvT, DIMC, qb, kb, vT, nullptr, nullptr);
  // 3. landmarks
  k_landmarks<<<(BHN*NM)/4, 256, 0, stream>>>(qb, kb, ql, klm, qlb, klmb);
  // 4. attn2 = softmax(ql@klm^T) via split MFMA + row normalize
  k_nat<0,4><<<dim3(8, BHN), 256, 0, stream>>>(ql, klm, nullptr, nullptr, nullptr, a2, DH);
  k_rowsm<<<BHN*NM/4, 256, 0, stream>>>(a2);
  // 5. pinv init
  k_zero_scal<<<1, 64, 0, stream>>>(scal);
  k_pinv_reduce<<<BHN, 256, 0, stream>>>(a2, scal);
  k_zinit<<<(int)(MM_E/256), 256, 0, stream>>>(a2, scal, zbuf);              // z0 = a2^T/c
  k_nat<0,1><<<dim3(8, BHN), 256, 0, stream>>>(a2, a2, nullptr, nullptr, scal, wb, NM); // w0 = a2@a2^T/c
  // 6. Newton-Schulz: w' = 3.25w - 0.25*s1@(15I-7w+s1); z' = 3.25z - 0.25*(z@w)@(15I-7w+s1)
  float* w = wb; float* wn = wnb; float* zc = zbuf; float* zn = znbuf;
  for (int it = 0; it < NITER; ++it) {
    k_nat<0,0><<<dim3(8, BHN), 256, 0, stream>>>(w, w, nullptr, nullptr, nullptr, s1, NM);
    k_nat<1,2><<<dim3(8, BHN), 256, 0, stream>>>(s1, s1, w, w, nullptr, wn, NM);
    k_nat<0,0><<<dim3(8, BHN), 256, 0, stream>>>(zc, w, nullptr, nullptr, nullptr, c1, NM);
    k_nat<1,2><<<dim3(8, BHN), 256, 0, stream>>>(c1, s1, w, zc, nullptr, zn, NM);
    float* tp = w; w = wn; wn = tp;
    tp = zc; zc = zn; zn = tp;
  }
  // 7. w1 = softmax(ql@k^T)@v (MFMA flash, sliced) -> w1T
  k_flash<0><<<dim3(NSLICE, BHN), 256, 0, stream>>>(qlb, kb, vT, fpart, nullptr);
  k_attn3v_combine<<<(BHN*NM)/4, 256, 0, stream>>>(fpart, w1T);
  // 8. w2T = (z@w1)^T  (native split MFMA)
  k_w2nat<<<dim3(4, BHN), 256, 0, stream>>>(w1T, zc, w2T);
  // 9. attn1 @ w2 -> outb (MFMA flash)
  k_flash<1><<<dim3(NSEQ/256, BHN), 256, 0, stream>>>(qb, klmb, w2T, nullptr, outb);
  // 10. conv residual
  k_conv_add<<<dim3(NSEQ/256, BHN), 256, 0, stream>>>(vT, w_conv, outb);
  // 11. output projection
  k_mgemm<1><<<dim3(256, 4), 256, 0, stream>>>(outb, woutT, DIMC, nullptr, nullptr, nullptr, b_out, out);
}

// Round 5
// 712.327 us; speedup vs baseline: 4.9099x; 1.1594x over previous
//
#include <hip/hip_runtime.h>
#include <cstdint>
#include <cstddef>

#define BQ 4
#define NSEQ 8192
#define DIMC 512
#define NH 8
#define DH 64
#define NM 256
#define NITER 6
#define KW 33
#define BHN (BQ*NH)
#define NSLICE 8

typedef unsigned short bf16u;
typedef __attribute__((ext_vector_type(8))) short short8;
typedef __attribute__((ext_vector_type(4))) float f32x4;
#define MFMA16(a,b,c) __builtin_amdgcn_mfma_f32_16x16x32_bf16(a,b,c,0,0,0)

__device__ inline float b2f(bf16u u) { return __uint_as_float(((unsigned int)u) << 16); }
__device__ inline bf16u f2b(float f) {
  unsigned int u = __float_as_uint(f);
  unsigned int r = (u + 0x7fffu + ((u >> 16) & 1u)) >> 16;  // RNE
  return (bf16u)r;
}
// truncation split: v = hi + lo + O(2^-17 |v|)
__device__ inline void splt(float v, unsigned short& h, unsigned short& l) {
  unsigned u = __float_as_uint(v);
  h = (unsigned short)(u >> 16);
  float hf = __uint_as_float(u & 0xffff0000u);
  l = (unsigned short)(__float_as_uint(v - hf) >> 16);
}

__global__ __launch_bounds__(256) void k_fill(float* out, int n, float v) {
  int i = blockIdx.x * 256 + threadIdx.x;
  if (i < n) out[i] = v;
}

// ---------------- fp32 -> bf16 elementwise (8 per thread)
__global__ __launch_bounds__(256) void c_f2b(const float* __restrict__ src, bf16u* __restrict__ dst, int n8) {
  int i = blockIdx.x*256 + threadIdx.x;
  if (i < n8) {
    const float4* s = (const float4*)(src + (size_t)i*8);
    float4 a = s[0], b = s[1];
    ushort4 lo, hi;
    lo.x=f2b(a.x); lo.y=f2b(a.y); lo.z=f2b(a.z); lo.w=f2b(a.w);
    hi.x=f2b(b.x); hi.y=f2b(b.y); hi.z=f2b(b.z); hi.w=f2b(b.w);
    ushort4* d = (ushort4*)(dst + (size_t)i*8);
    d[0] = lo; d[1] = hi;
  }
}

// ---------------- fp32 [R][C] -> bf16 transposed [C][R]
__global__ __launch_bounds__(256) void c_transb(const float* __restrict__ w, bf16u* __restrict__ wT, int R, int C) {
  int i = blockIdx.x*256 + threadIdx.x;
  if (i < R*C) {
    int r = i / C, c = i - r*C;
    wT[(size_t)c*R + r] = f2b(w[i]);
  }
}

// ---------------- MFMA GEMM  C[M,-] = A[M,K](bf16) @ Bt[N,K]^T(bf16)
// XCD-chunked block swizzle: m-strip-major per XCD so n-siblings share L2.
template<int MODE>
__global__ __launch_bounds__(256) void k_mgemm(
    const bf16u* __restrict__ A, const bf16u* __restrict__ Bt, int K, int nb,
    bf16u* __restrict__ oq, bf16u* __restrict__ ok, bf16u* __restrict__ ovT,
    const float* __restrict__ bias, float* __restrict__ oC) {
  __shared__ short As[128][72];
  __shared__ short Bs[128][72];
  const int id = blockIdx.x;
  const int rid = (id & 7) * ((int)gridDim.x >> 3) + (id >> 3);
  const int m0 = (rid / nb) * 128, n0 = (rid % nb) * 128;
  const int t = threadIdx.x;
  const int wid = t>>6, l = t&63, lm = l&15, lg = l>>4;
  const int wr = (wid>>1)*64, wc = (wid&1)*64;
  f32x4 acc[4][4];
  #pragma unroll
  for (int i=0;i<4;++i)
    #pragma unroll
    for (int j=0;j<4;++j) acc[i][j] = (f32x4){0,0,0,0};
  for (int k0=0; k0<K; k0+=64) {
    #pragma unroll
    for (int i=0;i<4;++i) {
      int c = t + i*256;
      int row = c>>3, kc = (c&7)<<3;
      *(uint4*)&As[row][kc] = *(const uint4*)(A  + (size_t)(m0+row)*K + k0+kc);
      *(uint4*)&Bs[row][kc] = *(const uint4*)(Bt + (size_t)(n0+row)*K + k0+kc);
    }
    __syncthreads();
    #pragma unroll
    for (int ks=0;ks<2;++ks) {
      short8 af[4], bfr[4];
      #pragma unroll
      for (int i=0;i<4;++i) {
        af[i]  = *(const short8*)&As[wr+i*16+lm][ks*32+lg*8];
        bfr[i] = *(const short8*)&Bs[wc+i*16+lm][ks*32+lg*8];
      }
      #pragma unroll
      for (int i=0;i<4;++i)
        #pragma unroll
        for (int j=0;j<4;++j)
          acc[i][j] = MFMA16(af[i], bfr[j], acc[i][j]);
    }
    __syncthreads();
  }
  if (MODE==0) {
    #pragma unroll
    for (int mt=0;mt<4;++mt) {
      int grb = m0 + wr + mt*16 + lg*4;
      int b_ = grb>>13, nrow = grb & (NSEQ-1);
      #pragma unroll
      for (int nt=0;nt<4;++nt) {
        int gc = n0 + wc + nt*16 + lm;
        int which = gc>>9, h_ = (gc>>6)&7, d = gc&63;
        if (which==2) {
          ushort4 pk;
          pk.x=f2b(acc[mt][nt][0]); pk.y=f2b(acc[mt][nt][1]);
          pk.z=f2b(acc[mt][nt][2]); pk.w=f2b(acc[mt][nt][3]);
          *(ushort4*)(ovT + (((size_t)b_*NH+h_)*DH + d)*NSEQ + nrow) = pk;
        } else {
          bf16u* dst = (which==0) ? oq : ok;
          float mul = (which==0) ? 0.125f : 1.0f;
          #pragma unroll
          for (int r=0;r<4;++r)
            dst[(((size_t)b_*NH+h_)*NSEQ + nrow + r)*DH + d] = f2b(acc[mt][nt][r]*mul);
        }
      }
    }
  } else {
    #pragma unroll
    for (int mt=0;mt<4;++mt)
      #pragma unroll
      for (int r=0;r<4;++r) {
        int gr = m0 + wr + mt*16 + lg*4 + r;
        #pragma unroll
        for (int nt=0;nt<4;++nt) {
          int gc = n0 + wc + nt*16 + lm;
          oC[(size_t)gr*DIMC + gc] = acc[mt][nt][r] + bias[gc];
        }
      }
  }
}

// ---------------- landmark means over blocks of 32
__global__ __launch_bounds__(256) void k_landmarks(
    const bf16u* __restrict__ q, const bf16u* __restrict__ kbuf,
    float* __restrict__ ql, float* __restrict__ klm,
    bf16u* __restrict__ qlb, bf16u* __restrict__ klmb) {
  int gi = blockIdx.x*4 + (threadIdx.x>>6);
  int d = threadIdx.x & 63;
  int bh = gi >> 8, i = gi & 255;
  size_t srcoff = ((size_t)bh*NSEQ + (size_t)i*32)*DH + d;
  float sq = 0, sk = 0;
  #pragma unroll
  for (int j = 0; j < 32; ++j) {
    sq += b2f(q[srcoff + (size_t)j*DH]);
    sk += b2f(kbuf[srcoff + (size_t)j*DH]);
  }
  float mq = sq * (1.0f/32.0f), mk = sk * (1.0f/32.0f);
  ql[(size_t)gi*DH + d]  = mq;  klm[(size_t)gi*DH + d]  = mk;
  qlb[(size_t)gi*DH + d] = f2b(mq); klmb[(size_t)gi*DH + d] = f2b(mk);
}

// ---------------- split-bf16 MFMA GEMM for attn2: C = exp(A @ S^T), in-loader split
__global__ __launch_bounds__(256) void k_qlk_exp(
    const float* __restrict__ A, const float* __restrict__ S, float* __restrict__ C, int K) {
  __shared__ short Ah[128][40], Al[128][40], Bh[64][40], Bl[64][40];
  const int bh = blockIdx.y;
  const size_t abase = (size_t)bh*256*K;
  const size_t cbase = (size_t)bh<<16;
  const int m0 = (blockIdx.x & 1)*128, n0 = (blockIdx.x >> 1)*64;
  const int t = threadIdx.x;
  const int wid = t>>6, l = t&63, lm = l&15, lg = l>>4;
  const int wr = (wid&1)*64, wc = (wid>>1)*32;
  f32x4 acc[4][2];
  #pragma unroll
  for (int i=0;i<4;++i) { acc[i][0] = (f32x4){0,0,0,0}; acc[i][1] = (f32x4){0,0,0,0}; }
  for (int k0=0; k0<K; k0+=32) {
    #pragma unroll
    for (int i=0;i<4;++i) {
      int idx = t + i*256;
      int row = idx>>3, kc = (idx&7)<<2;
      float4 v = *(const float4*)(A + abase + (size_t)(m0+row)*K + k0+kc);
      ushort4 hh, ll;
      splt(v.x, hh.x, ll.x); splt(v.y, hh.y, ll.y);
      splt(v.z, hh.z, ll.z); splt(v.w, hh.w, ll.w);
      *(ushort4*)&Ah[row][kc] = hh; *(ushort4*)&Al[row][kc] = ll;
    }
    #pragma unroll
    for (int i=0;i<2;++i) {
      int idx = t + i*256;
      int row = idx>>3, kc = (idx&7)<<2;
      float4 v = *(const float4*)(S + abase + (size_t)(n0+row)*K + k0+kc);
      ushort4 hh, ll;
      splt(v.x, hh.x, ll.x); splt(v.y, hh.y, ll.y);
      splt(v.z, hh.z, ll.z); splt(v.w, hh.w, ll.w);
      *(ushort4*)&Bh[row][kc] = hh; *(ushort4*)&Bl[row][kc] = ll;
    }
    __syncthreads();
    short8 ah[4], al[4], sh[2], sl[2];
    #pragma unroll
    for (int mt=0;mt<4;++mt) {
      ah[mt] = *(const short8*)&Ah[wr+mt*16+lm][lg*8];
      al[mt] = *(const short8*)&Al[wr+mt*16+lm][lg*8];
    }
    #pragma unroll
    for (int nt=0;nt<2;++nt) {
      sh[nt] = *(const short8*)&Bh[wc+nt*16+lm][lg*8];
      sl[nt] = *(const short8*)&Bl[wc+nt*16+lm][lg*8];
    }
    #pragma unroll
    for (int mt=0;mt<4;++mt)
      #pragma unroll
      for (int nt=0;nt<2;++nt) {
        acc[mt][nt] = MFMA16(ah[mt], sh[nt], acc[mt][nt]);
        acc[mt][nt] = MFMA16(ah[mt], sl[nt], acc[mt][nt]);
        acc[mt][nt] = MFMA16(al[mt], sh[nt], acc[mt][nt]);
      }
    __syncthreads();
  }
  #pragma unroll
  for (int mt=0;mt<4;++mt)
    #pragma unroll
    for (int nt=0;nt<2;++nt)
      #pragma unroll
      for (int r=0;r<4;++r) {
        int gr = m0 + wr + mt*16 + lg*4 + r;
        int gc = n0 + wc + nt*16 + lm;
        C[cbase + (size_t)gr*256 + gc] = __expf(acc[mt][nt][r]);
      }
}

// ---------------- row softmax-normalize
__global__ __launch_bounds__(256) void k_rowsm(float* __restrict__ a2) {
  int row = blockIdx.x*4 + (threadIdx.x>>6);
  int l = threadIdx.x & 63;
  float4* p = (float4*)(a2 + (size_t)row*256 + l*4);
  float4 v = *p;
  float s = v.x+v.y+v.z+v.w;
  #pragma unroll
  for (int d=1; d<64; d<<=1) s += __shfl_xor(s, d);
  float inv = 1.0f/s;
  v.x*=inv; v.y*=inv; v.z*=inv; v.w*=inv;
  *p = v;
}

// ---------------- pinv init reductions
__global__ void k_zero_scal(unsigned* scal) { if (threadIdx.x < 2) scal[threadIdx.x] = 0u; }

__global__ __launch_bounds__(256) void k_pinv_reduce(const float* __restrict__ a2, unsigned* scal) {
  int bh = blockIdx.x, t = threadIdx.x;
  const float* A = a2 + (size_t)bh*NM*NM;
  float rs = 0, cs = 0;
  for (int j = 0; j < NM; ++j) rs += fabsf(A[(size_t)t*NM + j]);
  for (int i = 0; i < NM; ++i) cs += fabsf(A[(size_t)i*NM + t]);
  __shared__ float red[256];
  red[t] = rs; __syncthreads();
  for (int s = 128; s > 0; s >>= 1) { if (t < s) red[t] = fmaxf(red[t], red[t+s]); __syncthreads(); }
  if (t == 0) atomicMax(scal+0, __float_as_uint(red[0]));
  __syncthreads();
  red[t] = cs; __syncthreads();
  for (int s = 128; s > 0; s >>= 1) { if (t < s) red[t] = fmaxf(red[t], red[t+s]); __syncthreads(); }
  if (t == 0) atomicMax(scal+1, __float_as_uint(red[0]));
}

// ---------------- split a2 -> a2 hi/lo planes; zc = a2^T/c -> hi/lo planes (LDS transpose)
__global__ __launch_bounds__(256) void k_split_init(
    const float* __restrict__ a2, const unsigned* __restrict__ scal,
    bf16u* __restrict__ a2h, bf16u* __restrict__ a2l,
    bf16u* __restrict__ zch, bf16u* __restrict__ zcl) {
  __shared__ bf16u Th[64][72], Tl[64][72];
  const int bh = blockIdx.y;
  const int tx = blockIdx.x & 3, ty = blockIdx.x >> 2;
  const int r0 = ty*64, c0 = tx*64;
  const size_t base = (size_t)bh<<16;
  const int t = threadIdx.x;
  const float rc = 1.0f/(__uint_as_float(scal[0]) * __uint_as_float(scal[1]));
  {
    int rr = t>>2, cc0 = (t&3)*16;
    const float* src = a2 + base + (size_t)(r0+rr)*256 + c0+cc0;
    bf16u hbuf[16], lbuf[16];
    #pragma unroll
    for (int u=0;u<4;++u) {
      float4 v = *(const float4*)(src + u*4);
      float vv[4] = {v.x,v.y,v.z,v.w};
      #pragma unroll
      for (int e=0;e<4;++e) {
        splt(vv[e], hbuf[u*4+e], lbuf[u*4+e]);
        bf16u zh_, zl_;
        splt(vv[e]*rc, zh_, zl_);
        Th[cc0+u*4+e][rr] = zh_;
        Tl[cc0+u*4+e][rr] = zl_;
      }
    }
    bf16u* dh = a2h + base + (size_t)(r0+rr)*256 + c0+cc0;
    bf16u* dl = a2l + base + (size_t)(r0+rr)*256 + c0+cc0;
    #pragma unroll
    for (int u=0;u<4;++u) {
      *(ushort4*)(dh + u*4) = *(ushort4*)&hbuf[u*4];
      *(ushort4*)(dl + u*4) = *(ushort4*)&lbuf[u*4];
    }
  }
  __syncthreads();
  {
    int cc = t>>2, rr0 = (t&3)*16;
    bf16u* dh = zch + base + (size_t)(c0+cc)*256 + r0+rr0;
    bf16u* dl = zcl + base + (size_t)(c0+cc)*256 + r0+rr0;
    #pragma unroll
    for (int u=0;u<4;++u) {
      *(ushort4*)(dh + u*4) = *(ushort4*)&Th[cc][rr0+u*4];
      *(ushort4*)(dl + u*4) = *(ushort4*)&Tl[cc][rr0+u*4];
    }
  }
}

// ---------------- NS pre-split pair GEMM.  C = A@B^T (B symmetric), 3-MFMA split products.
// PHASE 0: out = acc/(s0*s1) -> O planes              (z=0 only)
// PHASE 1: z0: s=acc -> O planes; comb=15I-7*X+s -> C planes.  z1: acc -> O2 planes.
// PHASE 2: z0: 3.25*X - 0.25*acc -> O (in-place over X ok).  z1: 3.25*X2 - 0.25*acc -> O2.
template<int PHASE>
__global__ __launch_bounds__(256) void k_ns(
    const bf16u* __restrict__ Ah, const bf16u* __restrict__ Al,
    const bf16u* __restrict__ A2h, const bf16u* __restrict__ A2l,
    const bf16u* __restrict__ Bh_, const bf16u* __restrict__ Bl_,
    const bf16u* __restrict__ Xh, const bf16u* __restrict__ Xl,
    const bf16u* __restrict__ X2h, const bf16u* __restrict__ X2l,
    bf16u* __restrict__ Oh, bf16u* __restrict__ Ol,
    bf16u* __restrict__ O2h, bf16u* __restrict__ O2l,
    bf16u* __restrict__ Ch, bf16u* __restrict__ Cl,
    const unsigned* __restrict__ scal) {
  __shared__ short AhS[128][36], AlS[128][36], BhS[64][36], BlS[64][36];
  const int z = (gridDim.z == 2) ? blockIdx.z : (PHASE==2 ? 1 : 0);
  const int bh = blockIdx.y;
  const size_t base = (size_t)bh<<16;
  const int m0 = (blockIdx.x & 1)*128, n0 = (blockIdx.x >> 1)*64;
  const int t = threadIdx.x;
  const int wid = t>>6, l = t&63, lm = l&15, lg = l>>4;
  const int wr = (wid&1)*64, wc = (wid>>1)*32;
  const bf16u* pAh = z ? A2h : Ah;
  const bf16u* pAl = z ? A2l : Al;
  f32x4 acc[4][2];
  #pragma unroll
  for (int i=0;i<4;++i) { acc[i][0] = (f32x4){0,0,0,0}; acc[i][1] = (f32x4){0,0,0,0}; }
  for (int k0=0; k0<256; k0+=32) {
    #pragma unroll
    for (int i=0;i<2;++i) {
      int idx = t + i*256;
      int row = idx>>2, ch = (idx&3)<<3;
      *(uint4*)&AhS[row][ch] = *(const uint4*)(pAh + base + (size_t)(m0+row)*256 + k0+ch);
      *(uint4*)&AlS[row][ch] = *(const uint4*)(pAl + base + (size_t)(m0+row)*256 + k0+ch);
    }
    {
      int row = t>>2, ch = (t&3)<<3;
      *(uint4*)&BhS[row][ch] = *(const uint4*)(Bh_ + base + (size_t)(n0+row)*256 + k0+ch);
      *(uint4*)&BlS[row][ch] = *(const uint4*)(Bl_ + base + (size_t)(n0+row)*256 + k0+ch);
    }
    __syncthreads();
    short8 ah[4], al[4], sh[2], sl[2];
    #pragma unroll
    for (int mt=0;mt<4;++mt) {
      ah[mt] = *(const short8*)&AhS[wr+mt*16+lm][lg*8];
      al[mt] = *(const short8*)&AlS[wr+mt*16+lm][lg*8];
    }
    #pragma unroll
    for (int nt=0;nt<2;++nt) {
      sh[nt] = *(const short8*)&BhS[wc+nt*16+lm][lg*8];
      sl[nt] = *(const short8*)&BlS[wc+nt*16+lm][lg*8];
    }
    #pragma unroll
    for (int mt=0;mt<4;++mt)
      #pragma unroll
      for (int nt=0;nt<2;++nt) {
        acc[mt][nt] = MFMA16(ah[mt], sh[nt], acc[mt][nt]);
        acc[mt][nt] = MFMA16(ah[mt], sl[nt], acc[mt][nt]);
        acc[mt][nt] = MFMA16(al[mt], sh[nt], acc[mt][nt]);
      }
    __syncthreads();
  }
  float rc = 1.0f;
  if (PHASE==0) rc = 1.0f/(__uint_as_float(scal[0]) * __uint_as_float(scal[1]));
  #pragma unroll
  for (int mt=0;mt<4;++mt)
    #pragma unroll
    for (int nt=0;nt<2;++nt)
      #pragma unroll
      for (int r=0;r<4;++r) {
        int gr = m0 + wr + mt*16 + lg*4 + r;
        int gc = n0 + wc + nt*16 + lm;
        size_t idx = base + (size_t)gr*256 + gc;
        float a = acc[mt][nt][r];
        bf16u hh, ll;
        if (PHASE==0) {
          splt(a*rc, hh, ll); Oh[idx]=hh; Ol[idx]=ll;
        } else if (PHASE==1) {
          if (z==0) {
            splt(a, hh, ll); Oh[idx]=hh; Ol[idx]=ll;
            float wv = b2f(Xh[idx]) + b2f(Xl[idx]);
            float cb = ((gr==gc)?15.0f:0.0f) - 7.0f*wv + a;
            splt(cb, hh, ll); Ch[idx]=hh; Cl[idx]=ll;
          } else {
            splt(a, hh, ll); O2h[idx]=hh; O2l[idx]=ll;
          }
        } else {
          if (z==0) {
            float xv = b2f(Xh[idx]) + b2f(Xl[idx]);
            splt(3.25f*xv - 0.25f*a, hh, ll); Oh[idx]=hh; Ol[idx]=ll;
          } else {
            float xv = b2f(X2h[idx]) + b2f(X2l[idx]);
            splt(3.25f*xv - 0.25f*a, hh, ll); O2h[idx]=hh; O2l[idx]=ll;
          }
        }
      }
}

// ---------------- fused MFMA flash attention (no max-subtraction)
template<int MODE>
__global__ __launch_bounds__(256) void k_flash(
    const bf16u* __restrict__ qg, const bf16u* __restrict__ kg,
    const bf16u* __restrict__ vtg, float* __restrict__ fpart, bf16u* __restrict__ outb) {
  constexpr int NCH = (MODE==0) ? 16 : 4;
  const int bh = blockIdx.y;
  const int tile = blockIdx.x;
  const int t = threadIdx.x;
  const int wid = t>>6, l = t&63, lm = l&15, lg = l>>4;
  const size_t NQbase = (MODE==0) ? ((size_t)bh*NM) : ((size_t)bh*NSEQ + (size_t)tile*256);
  const int NJ = (MODE==0) ? NSEQ : NM;
  const int j0base = (MODE==0) ? tile*1024 : 0;

  __shared__ short Ks[64][72];
  __shared__ short Vs[64][72];
  __shared__ short Pt[4][64][72];

  short8 qf[4][2];
  {
    const bf16u* qrow = qg + (NQbase + (size_t)wid*64) * DH;
    #pragma unroll
    for (int mt=0;mt<4;++mt)
      #pragma unroll
      for (int ks=0;ks<2;++ks)
        qf[mt][ks] = *(const short8*)(qrow + (size_t)(mt*16+lm)*DH + ks*32 + lg*8);
  }
  f32x4 oacc[4][4];
  #pragma unroll
  for (int i=0;i<4;++i)
    #pragma unroll
    for (int j=0;j<4;++j) oacc[i][j] = (f32x4){0,0,0,0};
  float rs[4][4];
  #pragma unroll
  for (int i=0;i<4;++i) { rs[i][0]=0; rs[i][1]=0; rs[i][2]=0; rs[i][3]=0; }

  const bf16u* kbh = kg  + (size_t)bh*NJ*DH;
  const bf16u* vbh = vtg + (size_t)bh*DH*NJ;

  for (int ch=0; ch<NCH; ++ch) {
    int j0 = j0base + ch*64;
    #pragma unroll
    for (int i=0;i<2;++i) {
      int c = t + i*256;
      int row = c>>3, kc = (c&7)<<3;
      *(uint4*)&Ks[row][kc] = *(const uint4*)(kbh + (size_t)(j0+row)*DH + kc);
      *(uint4*)&Vs[row][kc] = *(const uint4*)(vbh + (size_t)row*NJ + j0 + kc);
    }
    __syncthreads();
    short8 kf[4][2];
    #pragma unroll
    for (int jt=0;jt<4;++jt)
      #pragma unroll
      for (int ks=0;ks<2;++ks)
        kf[jt][ks] = *(const short8*)&Ks[jt*16+lm][ks*32+lg*8];
    #pragma unroll
    for (int mt=0;mt<4;++mt) {
      #pragma unroll
      for (int jt=0;jt<4;++jt) {
        f32x4 s = (f32x4){0,0,0,0};
        s = MFMA16(qf[mt][0], kf[jt][0], s);
        s = MFMA16(qf[mt][1], kf[jt][1], s);
        #pragma unroll
        for (int r=0;r<4;++r) {
          float p = __expf(s[r]);
          rs[mt][r] += p;
          Pt[wid][mt*16+lg*4+r][jt*16+lm] = f2b(p);
        }
      }
    }
    short8 vf[4][2];
    #pragma unroll
    for (int dt=0;dt<4;++dt)
      #pragma unroll
      for (int jw=0;jw<2;++jw)
        vf[dt][jw] = *(const short8*)&Vs[dt*16+lm][jw*32+lg*8];
    #pragma unroll
    for (int mt=0;mt<4;++mt) {
      short8 pa0 = *(const short8*)&Pt[wid][mt*16+lm][lg*8];
      short8 pa1 = *(const short8*)&Pt[wid][mt*16+lm][32+lg*8];
      #pragma unroll
      for (int dt=0;dt<4;++dt) {
        oacc[mt][dt] = MFMA16(pa0, vf[dt][0], oacc[mt][dt]);
        oacc[mt][dt] = MFMA16(pa1, vf[dt][1], oacc[mt][dt]);
      }
    }
    __syncthreads();
  }
  #pragma unroll
  for (int mt=0;mt<4;++mt)
    #pragma unroll
    for (int r=0;r<4;++r) {
      float v = rs[mt][r];
      v += __shfl_xor(v, 1); v += __shfl_xor(v, 2);
      v += __shfl_xor(v, 4); v += __shfl_xor(v, 8);
      rs[mt][r] = v;
    }
  if (MODE==0) {
    float* fb = fpart + (((size_t)bh*NSLICE + tile)*NM)*65;
    #pragma unroll
    for (int mt=0;mt<4;++mt)
      #pragma unroll
      for (int r=0;r<4;++r) {
        int row = wid*64 + mt*16 + lg*4 + r;
        float* fr = fb + (size_t)row*65;
        #pragma unroll
        for (int dt=0;dt<4;++dt) fr[dt*16+lm] = oacc[mt][dt][r];
        if (lm==0) fr[64] = rs[mt][r];
      }
  } else {
    const int b_ = bh>>3, h_ = bh&7;
    #pragma unroll
    for (int mt=0;mt<4;++mt)
      #pragma unroll
      for (int r=0;r<4;++r) {
        float inv = 1.0f/rs[mt][r];
        int n = tile*256 + wid*64 + mt*16 + lg*4 + r;
        bf16u* orow = outb + ((size_t)b_*NSEQ + n)*DIMC + h_*DH;
        #pragma unroll
        for (int dt=0;dt<4;++dt)
          orow[dt*16+lm] = f2b(oacc[mt][dt][r]*inv);
      }
  }
}

// combine -> w1T fp32 [bh][64][256]
__global__ __launch_bounds__(256) void k_attn3v_combine(
    const float* __restrict__ fpart, float* __restrict__ w1T) {
  int gi = blockIdx.x*4 + (threadIdx.x>>6);
  int d = threadIdx.x & 63;
  int bh = gi >> 8, i = gi & 255;
  float accd = 0, ssum = 0;
  #pragma unroll
  for (int s = 0; s < NSLICE; ++s) {
    const float* fp = fpart + (((size_t)bh*NSLICE + s)*NM + i)*65;
    accd += fp[d];
    ssum += fp[64];
  }
  w1T[((size_t)bh*64 + d)*256 + i] = accd / ssum;
}

// ---------------- w2T[bh][64][256] = w1T @ z^T  (z planes pre-split; A split in-loader)
__global__ __launch_bounds__(256) void k_w2nat(
    const float* __restrict__ w1T, const bf16u* __restrict__ zh, const bf16u* __restrict__ zl,
    bf16u* __restrict__ w2T) {
  __shared__ short Ah[64][36], Al[64][36], Bh[64][36], Bl[64][36];
  const int bh = blockIdx.y;
  const int n0 = blockIdx.x*64;
  const size_t a0 = (size_t)bh*64*256;
  const size_t s0 = (size_t)bh<<16;
  const int t = threadIdx.x;
  const int wid = t>>6, l = t&63, lm = l&15, lg = l>>4;
  const int wc = wid*16;
  f32x4 acc[4];
  #pragma unroll
  for (int i=0;i<4;++i) acc[i] = (f32x4){0,0,0,0};
  for (int k0=0; k0<256; k0+=32) {
    #pragma unroll
    for (int i=0;i<2;++i) {
      int idx = t + i*256;
      int row = idx>>3, kc = (idx&7)<<2;
      float4 v = *(const float4*)(w1T + a0 + (size_t)row*256 + k0+kc);
      ushort4 hh, ll;
      splt(v.x, hh.x, ll.x); splt(v.y, hh.y, ll.y);
      splt(v.z, hh.z, ll.z); splt(v.w, hh.w, ll.w);
      *(ushort4*)&Ah[row][kc] = hh; *(ushort4*)&Al[row][kc] = ll;
    }
    {
      int row = t>>2, ch = (t&3)<<3;
      *(uint4*)&Bh[row][ch] = *(const uint4*)(zh + s0 + (size_t)(n0+row)*256 + k0+ch);
      *(uint4*)&Bl[row][ch] = *(const uint4*)(zl + s0 + (size_t)(n0+row)*256 + k0+ch);
    }
    __syncthreads();
    short8 sh = *(const short8*)&Bh[wc+lm][lg*8];
    short8 sl = *(const short8*)&Bl[wc+lm][lg*8];
    #pragma unroll
    for (int mt=0;mt<4;++mt) {
      short8 ah = *(const short8*)&Ah[mt*16+lm][lg*8];
      short8 al = *(const short8*)&Al[mt*16+lm][lg*8];
      acc[mt] = MFMA16(ah, sh, acc[mt]);
      acc[mt] = MFMA16(ah, sl, acc[mt]);
      acc[mt] = MFMA16(al, sh, acc[mt]);
    }
    __syncthreads();
  }
  #pragma unroll
  for (int mt=0;mt<4;++mt)
    #pragma unroll
    for (int r=0;r<4;++r) {
      int gm = mt*16 + lg*4 + r;
      w2T[a0 + (size_t)gm*256 + n0 + wc + lm] = f2b(acc[mt][r]);
    }
}

// ---------------- depthwise conv residual from vT, LDS-transposed staging
__global__ __launch_bounds__(256) void k_conv_add(
    const bf16u* __restrict__ vt, const float* __restrict__ wc, bf16u* __restrict__ outb) {
  __shared__ short Vs[288][72];
  __shared__ float Wsh[40];
  const int bh = blockIdx.y, n0 = blockIdx.x*256;
  const int b_ = bh>>3, h_ = bh&7;
  const int t = threadIdx.x;
  if (t < KW) Wsh[t] = wc[h_*KW + t];
  const bf16u* vrow = vt + (size_t)bh*DH*NSEQ;
  {
    int d = t&63, seg = t>>6;
    #pragma unroll
    for (int u=0; u<9; ++u) {
      int nl = seg*72 + u*8;
      int gn = n0 - 16 + nl;
      bf16u e8[8];
      if (gn >= 0 && gn + 8 <= NSEQ) {
        *(uint4*)e8 = *(const uint4*)(vrow + (size_t)d*NSEQ + gn);
      } else {
        #pragma unroll
        for (int e=0;e<8;++e) {
          int g = gn + e;
          e8[e] = (g>=0 && g<NSEQ) ? vrow[(size_t)d*NSEQ + g] : (bf16u)0;
        }
      }
      #pragma unroll
      for (int e=0;e<8;++e) Vs[nl+e][d] = e8[e];
    }
  }
  __syncthreads();
  const int d = t&63, q = t>>6;
  #pragma unroll
  for (int c2=0;c2<4;++c2) {
    int nb = q*64 + c2*16;
    float wv[48];
    #pragma unroll
    for (int i=0;i<48;++i) wv[i] = b2f(Vs[nb+i][d]);
    #pragma unroll
    for (int e=0;e<16;++e) {
      float s = 0;
      #pragma unroll
      for (int k=0;k<KW;++k) s = fmaf(wv[e+k], Wsh[k], s);
      size_t oi = ((size_t)b_*NSEQ + n0 + nb + e)*DIMC + h_*DH + d;
      outb[oi] = f2b(b2f(outb[oi]) + s);
    }
  }
}

extern "C" void kernel_launch(void* const* d_in, const int* in_sizes, int n_in,
                              void* d_out, int out_size, void* d_ws, size_t ws_size,
                              hipStream_t stream) {
  (void)in_sizes; (void)n_in;
  const float* x      = (const float*)d_in[0];
  const float* w_qkv  = (const float*)d_in[1];
  const float* w_out  = (const float*)d_in[2];
  const float* b_out  = (const float*)d_in[3];
  const float* w_conv = (const float*)d_in[4];
  float* out = (float*)d_out;

  const size_t QKV_E = (size_t)BHN*NSEQ*DH;   // 16,777,216
  const size_t LM_E  = (size_t)BHN*NM*DH;     // 524,288
  const size_t MM_E  = (size_t)BHN*NM*NM;     // 2,097,152
  const size_t PLSZ  = MM_E*2;                // one bf16 plane = 4 MiB

  char* p = (char*)d_ws;
  char* nsb   = p;          p += 10*PLSZ;     // 40 MiB: NS planes P0..P9
  bf16u* qb    = (bf16u*)p; p += QKV_E*2;     // 32
  bf16u* kb    = (bf16u*)p; p += QKV_E*2;     // 32 (-> outb)
  bf16u* vT    = (bf16u*)p; p += QKV_E*2;     // 32
  bf16u* wqkvT = (bf16u*)p; p += (size_t)DIMC*3*DIMC*2;
  bf16u* woutT = (bf16u*)p; p += (size_t)DIMC*DIMC*2;
  float* ql    = (float*)p; p += LM_E*4;
  float* klm   = (float*)p; p += LM_E*4;
  bf16u* qlb   = (bf16u*)p; p += LM_E*2;
  bf16u* klmb  = (bf16u*)p; p += LM_E*2;
  float* w1T   = (float*)p; p += LM_E*4;
  bf16u* w2T   = (bf16u*)p; p += LM_E*2;
  unsigned* scal = (unsigned*)p; p += 256;
  size_t need = (size_t)(p - (char*)d_ws);

  if (ws_size < need) {
    k_fill<<<(out_size + 255)/256, 256, 0, stream>>>(out, out_size, 12345.0f);
    return;
  }

  // NS plane map (each 4 MiB):
  bf16u* a2h  = (bf16u*)(nsb + 0*PLSZ);   // -> c1h after w0
  bf16u* a2l  = (bf16u*)(nsb + 1*PLSZ);   // -> c1l
  bf16u* s1h  = (bf16u*)(nsb + 2*PLSZ);
  bf16u* s1l  = (bf16u*)(nsb + 3*PLSZ);
  bf16u* cmh  = (bf16u*)(nsb + 4*PLSZ);
  bf16u* cml  = (bf16u*)(nsb + 5*PLSZ);
  bf16u* wh   = (bf16u*)(nsb + 6*PLSZ);
  bf16u* wl   = (bf16u*)(nsb + 7*PLSZ);
  bf16u* zch  = (bf16u*)(nsb + 8*PLSZ);
  bf16u* zcl  = (bf16u*)(nsb + 9*PLSZ);
  float* a2f  = (float*)(nsb + 2*PLSZ);   // fp32 a2 overlays s1 planes (dead before s1 written)
  float* fpart = (float*)nsb;             // 17 MiB over P0..P5 after NS done
  bf16u* c1h = a2h; bf16u* c1l = a2l;
  bf16u* xb  = qb;                        // stage x bf16 in qb (overwritten by qkv epilogue? NO -
  // xb must live through k_mgemm<0>. Use kb? kb written by epilogue too. Use vT? also written.
  // Safe: put xb in the NS region (32 MiB needed, NS region is 40 MiB, all dead at this point).
  xb = (bf16u*)nsb;

  // 1. converts
  c_f2b<<<(int)(QKV_E/8/256), 256, 0, stream>>>(x, xb, (int)(QKV_E/8));
  c_transb<<<(DIMC*3*DIMC+255)/256, 256, 0, stream>>>(w_qkv, wqkvT, DIMC, 3*DIMC);
  c_transb<<<(DIMC*DIMC+255)/256, 256, 0, stream>>>(w_out, woutT, DIMC, DIMC);
  // 2. qkv projection (MFMA, XCD-chunked swizzle)
  k_mgemm<0><<<3072, 256, 0, stream>>>(xb, wqkvT, DIMC, 12, qb, kb, vT, nullptr, nullptr);
  // 3. landmarks
  k_landmarks<<<(BHN*NM)/4, 256, 0, stream>>>(qb, kb, ql, klm, qlb, klmb);
  // 4. attn2 = softmax(ql@klm^T)
  k_qlk_exp<<<dim3(8, BHN), 256, 0, stream>>>(ql, klm, a2f, DH);
  k_rowsm<<<BHN*NM/4, 256, 0, stream>>>(a2f);
  // 5. pinv init
  k_zero_scal<<<1, 64, 0, stream>>>(scal);
  k_pinv_reduce<<<BHN, 256, 0, stream>>>(a2f, scal);
  k_split_init<<<dim3(16, BHN), 256, 0, stream>>>(a2f, scal, a2h, a2l, zch, zcl);
  // w0 = a2@a2^T/c
  k_ns<0><<<dim3(8, BHN, 1), 256, 0, stream>>>(
      a2h,a2l, nullptr,nullptr, a2h,a2l, nullptr,nullptr, nullptr,nullptr,
      wh,wl, nullptr,nullptr, nullptr,nullptr, scal);
  // 6. Newton-Schulz, 2 launches/iter, in-place w,z
  for (int it = 0; it < NITER; ++it) {
    k_ns<1><<<dim3(8, BHN, 2), 256, 0, stream>>>(
        wh,wl, zch,zcl, wh,wl, wh,wl, nullptr,nullptr,
        s1h,s1l, c1h,c1l, cmh,cml, nullptr);
    k_ns<2><<<dim3(8, BHN, (it==NITER-1)?1:2), 256, 0, stream>>>(
        s1h,s1l, c1h,c1l, cmh,cml, wh,wl, zch,zcl,
        wh,wl, zch,zcl, nullptr,nullptr, nullptr);
  }
  // 7. w1 = softmax(ql@k^T)@v (MFMA flash, sliced) -> w1T
  k_flash<0><<<dim3(NSLICE, BHN), 256, 0, stream>>>(qlb, kb, vT, fpart, nullptr);
  k_attn3v_combine<<<(BHN*NM)/4, 256, 0, stream>>>(fpart, w1T);
  // 8. w2T = w1T @ z^T
  k_w2nat<<<dim3(4, BHN), 256, 0, stream>>>(w1T, zch, zcl, w2T);
  // 9. attn1 @ w2 -> outb (MFMA flash)
  bf16u* outb = kb;
  k_flash<1><<<dim3(NSEQ/256, BHN), 256, 0, stream>>>(qb, klmb, w2T, nullptr, outb);
  // 10. conv residual
  k_conv_add<<<dim3(NSEQ/256, BHN), 256, 0, stream>>>(vT, w_conv, outb);
  // 11. output projection (XCD-chunked swizzle)
  k_mgemm<1><<<1024, 256, 0, stream>>>(outb, woutT, DIMC, 4, nullptr, nullptr, nullptr, b_out, out);
}